// Round 13
// baseline (284.781 us; speedup 1.0000x reference)
//
#include <hip/hip_runtime.h>
#include <stdint.h>

#define TPB 256
#define SPAN 512        // nodes per dest bucket (bucket = col>>9)
#define LSH 9           // log2(SPAN)
#define PART_B 256      // partition blocks (one per CU)
#define PART_T 1024     // threads in hist/partition kernels
#define MEGA_T 1024
#define SCAN_T 1024
#define SCAN_B 4096     // elements per scan block (1024 thr x 4)
#define SORT_CAP 35840  // words of dynamic LDS buffer (140KB); W ~32653±181 (+17sigma)

// ---------------------------------------------------------------------------
// GCN 3-layer forward on MI355X.
// R13: persistent mega-kernel. R12 (208us) profile: after p_part produces
// bucket-grouped edges, the sort+3-gather machinery re-streams 25.6MB edge
// data 4 more times (csr write + 3 csr reads) ~100us. Now ONE kernel
// (196 blocks x 1024thr, 150KB LDS = 1 block/CU, all co-resident) does:
// LDS counting sort of its bucket (kept resident) | dinv in LDS | dxw1 =
// dinv*(x@W1) own nodes | grid barrier | 3 gather layers from LDS edges
// with grid barriers between (device-scope atomic counter + __threadfence,
// which on gfx950 performs cross-XCD L2 writeback/inv). csr_row/indptr
// deleted. Statistical overflow (W>CAP, +17sigma) handled by LDS-atomic
// accumulate fallback branch. p_hist/scan/p_part unchanged from R12
// (p_part: amp 1.1 proven). R3 atomic-push fallback kept.
// ---------------------------------------------------------------------------

__global__ __launch_bounds__(256) void k_zero32(uint32_t* __restrict__ p, int n) {
    int i = blockIdx.x * 256 + threadIdx.x;
    if (i < n) p[i] = 0u;
}

// ---------------- bucket partition (unchanged from R12) ----------------

__global__ __launch_bounds__(PART_T) void p_hist(
    const int* __restrict__ col, uint32_t* __restrict__ H,
    int NB, int E, int PBE) {
    __shared__ uint32_t cnt[1024];
    for (int i = threadIdx.x; i < NB; i += PART_T) cnt[i] = 0u;
    __syncthreads();
    int blk = blockIdx.x;
    int s = blk * PBE, e = min(E, s + PBE);
    for (int i = s + threadIdx.x; i < e; i += PART_T)
        atomicAdd(&cnt[col[i] >> LSH], 1u);
    __syncthreads();
    for (int i = threadIdx.x; i < NB; i += PART_T)
        H[(size_t)i * PART_B + blk] = cnt[i];
}

__global__ __launch_bounds__(SCAN_T) void k_scan1(
    const unsigned int* __restrict__ in, unsigned int* __restrict__ partial,
    unsigned int* __restrict__ bsum, int M) {
    __shared__ unsigned int sm[SCAN_T];
    int tid  = threadIdx.x;
    int base = blockIdx.x * SCAN_B + tid * 4;
    unsigned int v0 = (base + 0 < M) ? in[base + 0] : 0u;
    unsigned int v1 = (base + 1 < M) ? in[base + 1] : 0u;
    unsigned int v2 = (base + 2 < M) ? in[base + 2] : 0u;
    unsigned int v3 = (base + 3 < M) ? in[base + 3] : 0u;
    unsigned int s = v0 + v1 + v2 + v3;
    sm[tid] = s;
    __syncthreads();
    for (int off = 1; off < SCAN_T; off <<= 1) {
        unsigned int t = (tid >= off) ? sm[tid - off] : 0u;
        __syncthreads();
        sm[tid] += t;
        __syncthreads();
    }
    unsigned int excl = sm[tid] - s;
    if (base + 0 < M) partial[base + 0] = excl;
    if (base + 1 < M) partial[base + 1] = excl + v0;
    if (base + 2 < M) partial[base + 2] = excl + v0 + v1;
    if (base + 3 < M) partial[base + 3] = excl + v0 + v1 + v2;
    if (tid == SCAN_T - 1) bsum[blockIdx.x] = sm[SCAN_T - 1];
}

__global__ void k_scan2(unsigned int* __restrict__ bsum, int nb) {
    if (threadIdx.x == 0 && blockIdx.x == 0) {
        unsigned int run = 0;
        for (int i = 0; i < nb; ++i) {
            unsigned int t = bsum[i];
            bsum[i] = run;
            run += t;
        }
    }
}

__global__ __launch_bounds__(TPB) void k_scan3(
    const unsigned int* __restrict__ partial, const unsigned int* __restrict__ bsum,
    unsigned int* __restrict__ outp, int M, int E) {
    int i = blockIdx.x * TPB + threadIdx.x;
    if (i < M) outp[i] = partial[i] + bsum[i / SCAN_B];
    if (i == 0) outp[M] = (unsigned int)E;
}

__global__ __launch_bounds__(PART_T) void p_part(
    const int* __restrict__ row, const int* __restrict__ col,
    const uint32_t* __restrict__ O, uint32_t* __restrict__ bpack,
    int NB, int E, int PBE) {
    __shared__ uint32_t cur[1024];
    int blk = blockIdx.x;
    for (int i = threadIdx.x; i < NB; i += PART_T)
        cur[i] = O[(size_t)i * PART_B + blk];
    __syncthreads();
    int s = blk * PBE, e = min(E, s + PBE);
    for (int i = s + threadIdx.x; i < e; i += PART_T) {
        int c = col[i];
        uint32_t slot = atomicAdd(&cur[c >> LSH], 1u);
        bpack[slot] = ((uint32_t)row[i] << LSH) | (uint32_t)(c & (SPAN - 1));
    }
}

// ---------------- persistent mega-kernel ----------------

__device__ __forceinline__ void gbar(uint32_t* cnt, uint32_t target) {
    __syncthreads();
    if (threadIdx.x == 0) {
        __threadfence();  // release: device-scope (cross-XCD L2 wb)
        __hip_atomic_fetch_add(cnt, 1u, __ATOMIC_ACQ_REL, __HIP_MEMORY_SCOPE_AGENT);
        while (__hip_atomic_load(cnt, __ATOMIC_ACQUIRE, __HIP_MEMORY_SCOPE_AGENT)
               < target) {
            __builtin_amdgcn_s_sleep(8);
        }
        __threadfence();  // acquire: invalidate stale cached lines
    }
    __syncthreads();
}

extern __shared__ uint32_t dyn_lds[];  // SORT_CAP words (sorted rows) / facc alias
__global__ __launch_bounds__(MEGA_T) void k_mega(
    const uint32_t* __restrict__ bpack, const uint32_t* __restrict__ O,
    const float* __restrict__ x,
    const float* __restrict__ W1, const float* __restrict__ b1,
    const float* __restrict__ W2, const float* __restrict__ b2,
    const float* __restrict__ W3, const float* __restrict__ b3,
    const float* __restrict__ Wc, const float* __restrict__ bc,
    float* __restrict__ dxw1, float* __restrict__ dxw2, float* __restrict__ dxw3,
    float* __restrict__ out, float* __restrict__ y3out,
    uint32_t* __restrict__ barcnt, int NB, int N, int E) {
    __shared__ uint32_t hist[SPAN];
    __shared__ uint32_t starts[SPAN + 1];
    __shared__ uint32_t cur[SPAN];
    __shared__ float    dinv_l[SPAN];
    __shared__ float    sW1[512];
    __shared__ float    sWs[48];  // [0:16)W2 [16:24)W3 [24:32)Wc [32:36)b1 [36:40)b2 [40:44)b3 [44:48)bc

    int b = blockIdx.x;
    int t = threadIdx.x;
    uint32_t s = O[(size_t)b * PART_B];
    uint32_t e = O[(size_t)(b + 1) * PART_B];  // b+1==NB -> O[M]==E
    uint32_t W = e - s;
    bool fits = (W <= (uint32_t)SORT_CAP);

    if (t < 512) sW1[t] = W1[t];
    if (t >= 512 && t < 560) {
        int i = t - 512;
        float v;
        if (i < 16)      v = W2[i];
        else if (i < 24) v = W3[i - 16];
        else if (i < 32) v = Wc[i - 24];
        else if (i < 36) v = b1[i - 32];
        else if (i < 40) v = b2[i - 36];
        else if (i < 44) v = b3[i - 40];
        else             v = bc[i - 44];
        sWs[i] = v;
    }
    if (t < SPAN) hist[t] = 0u;
    __syncthreads();

    // ---- Phase A: hist + scan (+ sort into LDS if fits) ----
    for (uint32_t i = s + t; i < e; i += MEGA_T)
        atomicAdd(&hist[bpack[i] & (SPAN - 1)], 1u);
    __syncthreads();
    if (t < SPAN) cur[t] = hist[t];
    __syncthreads();
    for (int off = 1; off < SPAN; off <<= 1) {
        uint32_t v = (t < SPAN && t >= off) ? cur[t - off] : 0u;
        __syncthreads();
        if (t < SPAN) cur[t] += v;
        __syncthreads();
    }
    if (t < SPAN) {
        uint32_t excl = cur[t] - hist[t];
        starts[t] = excl;
        cur[t]    = excl;
        dinv_l[t] = rsqrtf((float)(hist[t] + 1u));  // +1 = self loop
        if (t == SPAN - 1) starts[SPAN] = excl + hist[t];
    }
    __syncthreads();
    if (fits) {
        for (uint32_t i = s + t; i < e; i += MEGA_T) {
            uint32_t v = bpack[i];
            uint32_t slot = atomicAdd(&cur[v & (SPAN - 1)], 1u);
            dyn_lds[slot] = v >> LSH;
        }
        __syncthreads();
    }

    // ---- Phase B: dxw1 = dinv * (x @ W1) for own nodes (wave/node) ----
    int wid = t >> 6, lane = t & 63;
    for (int ld = wid; ld < SPAN; ld += (MEGA_T >> 6)) {
        int n = b * SPAN + ld;
        if (n >= N) break;
        float2 v = *(const float2*)(x + (size_t)n * 128 + 2 * lane);
        const float* w0 = &sW1[(2 * lane) * 4];
        const float* w1 = &sW1[(2 * lane + 1) * 4];
        float a[4];
#pragma unroll
        for (int j = 0; j < 4; ++j) a[j] = v.x * w0[j] + v.y * w1[j];
#pragma unroll
        for (int off = 32; off > 0; off >>= 1) {
#pragma unroll
            for (int j = 0; j < 4; ++j) a[j] += __shfl_down(a[j], off);
        }
        if (lane == 0) {
            float d = dinv_l[ld];
            *(float4*)(dxw1 + (size_t)n * 4) =
                make_float4(d * a[0], d * a[1], d * a[2], d * a[3]);
        }
    }
    gbar(barcnt, (uint32_t)NB * 1u);

    // ---- Phase C: layer-1 gather -> dxw2 (4-wide) ----
    const int PACC = SPAN + 8;
    if (fits) {
        int sub = t & 15;
        for (int ld = (t >> 4); ld < SPAN; ld += (MEGA_T >> 4)) {
            int n = b * SPAN + ld;
            if (n >= N) continue;
            uint32_t e0 = starts[ld], e1 = starts[ld + 1];
            float ax = 0.f, ay = 0.f, az = 0.f, aw = 0.f;
            for (uint32_t j = e0 + sub; j < e1; j += 16) {
                int r = (int)dyn_lds[j];
                float4 m = *(const float4*)(dxw1 + (size_t)r * 4);
                ax += m.x; ay += m.y; az += m.z; aw += m.w;
            }
#pragma unroll
            for (int off = 1; off < 16; off <<= 1) {
                ax += __shfl_xor(ax, off); ay += __shfl_xor(ay, off);
                az += __shfl_xor(az, off); aw += __shfl_xor(aw, off);
            }
            if (sub == 0) {
                float d = dinv_l[ld];
                float4 sv = *(const float4*)(dxw1 + (size_t)n * 4);
                float h0 = fmaxf(d * (ax + sv.x) + sWs[32], 0.f);
                float h1 = fmaxf(d * (ay + sv.y) + sWs[33], 0.f);
                float h2 = fmaxf(d * (az + sv.z) + sWs[34], 0.f);
                float h3 = fmaxf(d * (aw + sv.w) + sWs[35], 0.f);
                float o[4];
#pragma unroll
                for (int j = 0; j < 4; ++j)
                    o[j] = h0 * sWs[0 + j] + h1 * sWs[4 + j] +
                           h2 * sWs[8 + j] + h3 * sWs[12 + j];
                *(float4*)(dxw2 + (size_t)n * 4) =
                    make_float4(d * o[0], d * o[1], d * o[2], d * o[3]);
            }
        }
    } else {
        float* facc = (float*)dyn_lds;
        for (int i = t; i < 4 * PACC; i += MEGA_T) facc[i] = 0.f;
        __syncthreads();
        for (uint32_t i = s + t; i < e; i += MEGA_T) {
            uint32_t v = bpack[i];
            int r = (int)(v >> LSH), ld = (int)(v & (SPAN - 1));
            float4 m = *(const float4*)(dxw1 + (size_t)r * 4);
            atomicAdd(&facc[0 * PACC + ld], m.x);
            atomicAdd(&facc[1 * PACC + ld], m.y);
            atomicAdd(&facc[2 * PACC + ld], m.z);
            atomicAdd(&facc[3 * PACC + ld], m.w);
        }
        __syncthreads();
        int n = b * SPAN + t;
        if (t < SPAN && n < N) {
            float d = dinv_l[t];
            float4 sv = *(const float4*)(dxw1 + (size_t)n * 4);
            float h0 = fmaxf(d * (facc[0 * PACC + t] + sv.x) + sWs[32], 0.f);
            float h1 = fmaxf(d * (facc[1 * PACC + t] + sv.y) + sWs[33], 0.f);
            float h2 = fmaxf(d * (facc[2 * PACC + t] + sv.z) + sWs[34], 0.f);
            float h3 = fmaxf(d * (facc[3 * PACC + t] + sv.w) + sWs[35], 0.f);
            float o[4];
#pragma unroll
            for (int j = 0; j < 4; ++j)
                o[j] = h0 * sWs[0 + j] + h1 * sWs[4 + j] +
                       h2 * sWs[8 + j] + h3 * sWs[12 + j];
            *(float4*)(dxw2 + (size_t)n * 4) =
                make_float4(d * o[0], d * o[1], d * o[2], d * o[3]);
        }
        __syncthreads();
    }
    gbar(barcnt, (uint32_t)NB * 2u);

    // ---- Phase D: layer-2 gather -> dxw3 (4-in / 2-out) ----
    if (fits) {
        int sub = t & 15;
        for (int ld = (t >> 4); ld < SPAN; ld += (MEGA_T >> 4)) {
            int n = b * SPAN + ld;
            if (n >= N) continue;
            uint32_t e0 = starts[ld], e1 = starts[ld + 1];
            float ax = 0.f, ay = 0.f, az = 0.f, aw = 0.f;
            for (uint32_t j = e0 + sub; j < e1; j += 16) {
                int r = (int)dyn_lds[j];
                float4 m = *(const float4*)(dxw2 + (size_t)r * 4);
                ax += m.x; ay += m.y; az += m.z; aw += m.w;
            }
#pragma unroll
            for (int off = 1; off < 16; off <<= 1) {
                ax += __shfl_xor(ax, off); ay += __shfl_xor(ay, off);
                az += __shfl_xor(az, off); aw += __shfl_xor(aw, off);
            }
            if (sub == 0) {
                float d = dinv_l[ld];
                float4 sv = *(const float4*)(dxw2 + (size_t)n * 4);
                float h0 = fmaxf(d * (ax + sv.x) + sWs[36], 0.f);
                float h1 = fmaxf(d * (ay + sv.y) + sWs[37], 0.f);
                float h2 = fmaxf(d * (az + sv.z) + sWs[38], 0.f);
                float h3 = fmaxf(d * (aw + sv.w) + sWs[39], 0.f);
                float o0 = h0 * sWs[16] + h1 * sWs[18] + h2 * sWs[20] + h3 * sWs[22];
                float o1 = h0 * sWs[17] + h1 * sWs[19] + h2 * sWs[21] + h3 * sWs[23];
                *(float2*)(dxw3 + (size_t)n * 2) = make_float2(d * o0, d * o1);
            }
        }
    } else {
        float* facc = (float*)dyn_lds;
        for (int i = t; i < 4 * PACC; i += MEGA_T) facc[i] = 0.f;
        __syncthreads();
        for (uint32_t i = s + t; i < e; i += MEGA_T) {
            uint32_t v = bpack[i];
            int r = (int)(v >> LSH), ld = (int)(v & (SPAN - 1));
            float4 m = *(const float4*)(dxw2 + (size_t)r * 4);
            atomicAdd(&facc[0 * PACC + ld], m.x);
            atomicAdd(&facc[1 * PACC + ld], m.y);
            atomicAdd(&facc[2 * PACC + ld], m.z);
            atomicAdd(&facc[3 * PACC + ld], m.w);
        }
        __syncthreads();
        int n = b * SPAN + t;
        if (t < SPAN && n < N) {
            float d = dinv_l[t];
            float4 sv = *(const float4*)(dxw2 + (size_t)n * 4);
            float h0 = fmaxf(d * (facc[0 * PACC + t] + sv.x) + sWs[36], 0.f);
            float h1 = fmaxf(d * (facc[1 * PACC + t] + sv.y) + sWs[37], 0.f);
            float h2 = fmaxf(d * (facc[2 * PACC + t] + sv.z) + sWs[38], 0.f);
            float h3 = fmaxf(d * (facc[3 * PACC + t] + sv.w) + sWs[39], 0.f);
            float o0 = h0 * sWs[16] + h1 * sWs[18] + h2 * sWs[20] + h3 * sWs[22];
            float o1 = h0 * sWs[17] + h1 * sWs[19] + h2 * sWs[21] + h3 * sWs[23];
            *(float2*)(dxw3 + (size_t)n * 2) = make_float2(d * o0, d * o1);
        }
        __syncthreads();
    }
    gbar(barcnt, (uint32_t)NB * 3u);

    // ---- Phase E: layer-3 gather -> out, y3out (2-wide) ----
    if (fits) {
        int sub = t & 15;
        for (int ld = (t >> 4); ld < SPAN; ld += (MEGA_T >> 4)) {
            int n = b * SPAN + ld;
            if (n >= N) continue;
            uint32_t e0 = starts[ld], e1 = starts[ld + 1];
            float ax = 0.f, ay = 0.f;
            for (uint32_t j = e0 + sub; j < e1; j += 16) {
                int r = (int)dyn_lds[j];
                float2 m = *(const float2*)(dxw3 + (size_t)r * 2);
                ax += m.x; ay += m.y;
            }
#pragma unroll
            for (int off = 1; off < 16; off <<= 1) {
                ax += __shfl_xor(ax, off); ay += __shfl_xor(ay, off);
            }
            if (sub == 0) {
                float d = dinv_l[ld];
                float2 sv = *(const float2*)(dxw3 + (size_t)n * 2);
                float y0 = fmaxf(d * (ax + sv.x) + sWs[40], 0.f);
                float y1 = fmaxf(d * (ay + sv.y) + sWs[41], 0.f);
                float o[4];
#pragma unroll
                for (int j = 0; j < 4; ++j)
                    o[j] = y0 * sWs[24 + j] + y1 * sWs[28 + j] + sWs[44 + j];
                *(float4*)(out + (size_t)n * 4) = make_float4(o[0], o[1], o[2], o[3]);
                *(float2*)(y3out + (size_t)n * 2) = make_float2(y0, y1);
            }
        }
    } else {
        float* facc = (float*)dyn_lds;
        for (int i = t; i < 2 * PACC; i += MEGA_T) facc[i] = 0.f;
        __syncthreads();
        for (uint32_t i = s + t; i < e; i += MEGA_T) {
            uint32_t v = bpack[i];
            int r = (int)(v >> LSH), ld = (int)(v & (SPAN - 1));
            float2 m = *(const float2*)(dxw3 + (size_t)r * 2);
            atomicAdd(&facc[0 * PACC + ld], m.x);
            atomicAdd(&facc[1 * PACC + ld], m.y);
        }
        __syncthreads();
        int n = b * SPAN + t;
        if (t < SPAN && n < N) {
            float d = dinv_l[t];
            float2 sv = *(const float2*)(dxw3 + (size_t)n * 2);
            float y0 = fmaxf(d * (facc[0 * PACC + t] + sv.x) + sWs[40], 0.f);
            float y1 = fmaxf(d * (facc[1 * PACC + t] + sv.y) + sWs[41], 0.f);
            float o[4];
#pragma unroll
            for (int j = 0; j < 4; ++j)
                o[j] = y0 * sWs[24 + j] + y1 * sWs[28 + j] + sWs[44 + j];
            *(float4*)(out + (size_t)n * 4) = make_float4(o[0], o[1], o[2], o[3]);
            *(float2*)(y3out + (size_t)n * 2) = make_float2(y0, y1);
        }
    }
}

// ---------------- R3 fallback kernels (atomic push path) ----------------

__global__ __launch_bounds__(TPB) void k_zero_deg(unsigned int* __restrict__ deg, int N) {
    int i = blockIdx.x * TPB + threadIdx.x;
    if (i < N) deg[i] = 0u;
}

__global__ __launch_bounds__(TPB) void k_deg(
    const int* __restrict__ col, unsigned int* __restrict__ deg, int E) {
    int e = blockIdx.x * TPB + threadIdx.x;
    if (e >= E) return;
    atomicAdd(&deg[col[e]], 1u);
}

__global__ __launch_bounds__(TPB) void k_dinv(const unsigned int* __restrict__ deg,
                                              float* __restrict__ dinv, int N) {
    int i = blockIdx.x * TPB + threadIdx.x;
    if (i < N) dinv[i] = rsqrtf((float)(deg[i] + 1u));
}

__global__ __launch_bounds__(TPB) void k_xw1(
    const float* __restrict__ x, const float* __restrict__ W1,
    const float* __restrict__ dinv,
    float* __restrict__ xw, float* __restrict__ agg, int N) {
    __shared__ float sW[512];
    for (int t = threadIdx.x; t < 512; t += TPB) sW[t] = W1[t];
    __syncthreads();
    int gid  = blockIdx.x * TPB + threadIdx.x;
    int node = gid >> 6;
    int lane = threadIdx.x & 63;
    if (node >= N) return;
    float2 v = *(const float2*)(x + (size_t)node * 128 + 2 * lane);
    const float* w0 = &sW[(2 * lane) * 4];
    const float* w1 = &sW[(2 * lane + 1) * 4];
    float a[4];
#pragma unroll
    for (int j = 0; j < 4; ++j) a[j] = v.x * w0[j] + v.y * w1[j];
#pragma unroll
    for (int off = 32; off > 0; off >>= 1) {
#pragma unroll
        for (int j = 0; j < 4; ++j) a[j] += __shfl_down(a[j], off);
    }
    if (lane == 0) {
        float d  = dinv[node];
        float d2 = d * d;
        *(float4*)(xw  + (size_t)node * 4) = make_float4(a[0], a[1], a[2], a[3]);
        *(float4*)(agg + (size_t)node * 4) =
            make_float4(d2 * a[0], d2 * a[1], d2 * a[2], d2 * a[3]);
    }
}

__global__ __launch_bounds__(TPB) void k_prop4(
    const int* __restrict__ row, const int* __restrict__ col,
    const float* __restrict__ dinv,
    const float* __restrict__ xw, float* __restrict__ agg, int E) {
    int e = blockIdx.x * TPB + threadIdx.x;
    if (e >= E) return;
    int r = row[e];
    int c = col[e];
    float nv = dinv[r] * dinv[c];
    float4 m = *(const float4*)(xw + (size_t)r * 4);
    float* a = agg + (size_t)c * 4;
    atomicAdd(a + 0, nv * m.x);
    atomicAdd(a + 1, nv * m.y);
    atomicAdd(a + 2, nv * m.z);
    atomicAdd(a + 3, nv * m.w);
}

__global__ __launch_bounds__(TPB) void k_prop2(
    const int* __restrict__ row, const int* __restrict__ col,
    const float* __restrict__ dinv,
    const float* __restrict__ xw2, float* __restrict__ agg2, int E) {
    int e = blockIdx.x * TPB + threadIdx.x;
    if (e >= E) return;
    int r = row[e];
    int c = col[e];
    float nv = dinv[r] * dinv[c];
    float2 m = *(const float2*)(xw2 + (size_t)r * 2);
    float* a = agg2 + (size_t)c * 2;
    atomicAdd(a + 0, nv * m.x);
    atomicAdd(a + 1, nv * m.y);
}

__global__ __launch_bounds__(TPB) void k_node2(
    const float* __restrict__ b1, const float* __restrict__ W2,
    const float* __restrict__ dinv,
    float* __restrict__ xw, float* __restrict__ agg, int N) {
    int i = blockIdx.x * TPB + threadIdx.x;
    if (i >= N) return;
    float4 av = *(const float4*)(agg + (size_t)i * 4);
    float h0 = fmaxf(av.x + b1[0], 0.f);
    float h1 = fmaxf(av.y + b1[1], 0.f);
    float h2 = fmaxf(av.z + b1[2], 0.f);
    float h3 = fmaxf(av.w + b1[3], 0.f);
    float o[4];
#pragma unroll
    for (int j = 0; j < 4; ++j)
        o[j] = h0 * W2[0 * 4 + j] + h1 * W2[1 * 4 + j] +
               h2 * W2[2 * 4 + j] + h3 * W2[3 * 4 + j];
    float d  = dinv[i];
    float d2 = d * d;
    *(float4*)(xw  + (size_t)i * 4) = make_float4(o[0], o[1], o[2], o[3]);
    *(float4*)(agg + (size_t)i * 4) = make_float4(d2 * o[0], d2 * o[1], d2 * o[2], d2 * o[3]);
}

__global__ __launch_bounds__(TPB) void k_node3(
    const float* __restrict__ b2, const float* __restrict__ W3,
    const float* __restrict__ dinv,
    const float* __restrict__ agg,
    float* __restrict__ xw3, float* __restrict__ agg3, int N) {
    int i = blockIdx.x * TPB + threadIdx.x;
    if (i >= N) return;
    float4 av = *(const float4*)(agg + (size_t)i * 4);
    float h0 = fmaxf(av.x + b2[0], 0.f);
    float h1 = fmaxf(av.y + b2[1], 0.f);
    float h2 = fmaxf(av.z + b2[2], 0.f);
    float h3 = fmaxf(av.w + b2[3], 0.f);
    float o0 = h0 * W3[0] + h1 * W3[2] + h2 * W3[4] + h3 * W3[6];
    float o1 = h0 * W3[1] + h1 * W3[3] + h2 * W3[5] + h3 * W3[7];
    float d  = dinv[i];
    float d2 = d * d;
    *(float2*)(xw3  + (size_t)i * 2) = make_float2(o0, o1);
    *(float2*)(agg3 + (size_t)i * 2) = make_float2(d2 * o0, d2 * o1);
}

__global__ __launch_bounds__(TPB) void k_out(
    const float* __restrict__ b3, const float* __restrict__ Wc,
    const float* __restrict__ bc,
    const float* __restrict__ agg3,
    float* __restrict__ out, float* __restrict__ y3out, int N) {
    int i = blockIdx.x * TPB + threadIdx.x;
    if (i >= N) return;
    float2 av = *(const float2*)(agg3 + (size_t)i * 2);
    float y0 = fmaxf(av.x + b3[0], 0.f);
    float y1 = fmaxf(av.y + b3[1], 0.f);
    float o[4];
#pragma unroll
    for (int j = 0; j < 4; ++j)
        o[j] = y0 * Wc[0 * 4 + j] + y1 * Wc[1 * 4 + j] + bc[j];
    *(float4*)(out + (size_t)i * 4) = make_float4(o[0], o[1], o[2], o[3]);
    *(float2*)(y3out + (size_t)i * 2) = make_float2(y0, y1);
}

extern "C" void kernel_launch(void* const* d_in, const int* in_sizes, int n_in,
                              void* d_out, int out_size, void* d_ws, size_t ws_size,
                              hipStream_t stream) {
    const float* x  = (const float*)d_in[0];
    const int*   ei = (const int*)d_in[1];   // int32 (harness converts integer inputs)
    const float* W1 = (const float*)d_in[2];
    const float* b1 = (const float*)d_in[3];
    const float* W2 = (const float*)d_in[4];
    const float* b2 = (const float*)d_in[5];
    const float* W3 = (const float*)d_in[6];
    const float* b3 = (const float*)d_in[7];
    const float* Wc = (const float*)d_in[8];
    const float* bc = (const float*)d_in[9];

    const int N = in_sizes[0] / 128;
    const int E = in_sizes[1] / 2;

    const int* row = ei;
    const int* col = ei + (size_t)E;

    const int NB  = (N + SPAN - 1) / SPAN;        // dest buckets (196)
    const int M   = NB * PART_B;                  // flattened hist size (~50K)
    const int PBE = (E + PART_B - 1) / PART_B;    // edges per partition block

    float* out   = (float*)d_out;                  // [N,4]
    float* y3out = (float*)d_out + (size_t)N * 4;  // [N,2]

    const int nblkN = (N + TPB - 1) / TPB;
    const int nblkE = (E + TPB - 1) / TPB;
    const int nblkW = (N * 64 + TPB - 1) / TPB;
    const int nblkM = (M + 1 + TPB - 1) / TPB;
    const int nblkS = (M + SCAN_B - 1) / SCAN_B;

    // Carve (~30MB). H is scanned in place (becomes O).
    size_t off = 0;
    auto carve = [&](size_t bytes) -> void* {
        void* r = (void*)((char*)d_ws + off);
        off += (bytes + 255) & ~(size_t)255;
        return r;
    };
    float*    dxw1   = (float*)carve((size_t)N * 4 * 4);
    float*    dxw2   = (float*)carve((size_t)N * 4 * 4);
    float*    dxw3   = (float*)carve((size_t)N * 2 * 4);
    uint32_t* bsum   = (uint32_t*)carve(260 * 4);
    uint32_t* barcnt = (uint32_t*)carve(256 * 4);
    uint32_t* H      = (uint32_t*)carve(((size_t)M + 1) * 4);  // -> O in place
    uint32_t* bpack  = (uint32_t*)carve((size_t)E * 4);
    bool use_mega = (off <= ws_size) && (NB <= 256) && (NB <= 1024) &&
                    (N < (1 << 23));

    if (use_mega) {
        size_t sort_lds = (size_t)SORT_CAP * 4;  // 140KB dynamic (+~12KB static)
        hipFuncSetAttribute((const void*)k_mega,
                            hipFuncAttributeMaxDynamicSharedMemorySize,
                            (int)sort_lds);
        k_zero32<<<1, 256, 0, stream>>>(barcnt, 256);
        p_hist<<<PART_B, PART_T, 0, stream>>>(col, H, NB, E, PBE);
        k_scan1<<<nblkS, SCAN_T, 0, stream>>>(H, H, bsum, M);     // in-place
        k_scan2<<<1, 32, 0, stream>>>(bsum, nblkS);
        k_scan3<<<nblkM, TPB, 0, stream>>>(H, bsum, H, M, E);     // in-place
        p_part<<<PART_B, PART_T, 0, stream>>>(row, col, H, bpack, NB, E, PBE);
        k_mega<<<NB, MEGA_T, sort_lds, stream>>>(bpack, H, x,
                                                 W1, b1, W2, b2, W3, b3, Wc, bc,
                                                 dxw1, dxw2, dxw3, out, y3out,
                                                 barcnt, NB, N, E);
    } else {
        // R3 verified atomic-push fallback: recarve from base (~6MB).
        size_t foff = 0;
        auto fcarve = [&](size_t bytes) -> void* {
            void* r = (void*)((char*)d_ws + foff);
            foff += (bytes + 255) & ~(size_t)255;
            return r;
        };
        unsigned int* deg   = (unsigned int*)fcarve((size_t)N * 4);
        float*        fdinv = (float*)fcarve((size_t)N * 4);
        float*        xw    = (float*)fcarve((size_t)N * 4 * 4);
        float*        agg   = (float*)fcarve((size_t)N * 4 * 4);
        float*        xw3   = (float*)fcarve((size_t)N * 2 * 4);
        float*        agg3  = (float*)fcarve((size_t)N * 2 * 4);
        k_zero_deg<<<nblkN, TPB, 0, stream>>>(deg, N);
        k_deg<<<nblkE, TPB, 0, stream>>>(col, deg, E);
        k_dinv<<<nblkN, TPB, 0, stream>>>(deg, fdinv, N);
        k_xw1<<<nblkW, TPB, 0, stream>>>(x, W1, fdinv, xw, agg, N);
        k_prop4<<<nblkE, TPB, 0, stream>>>(row, col, fdinv, xw, agg, E);
        k_node2<<<nblkN, TPB, 0, stream>>>(b1, W2, fdinv, xw, agg, N);
        k_prop4<<<nblkE, TPB, 0, stream>>>(row, col, fdinv, xw, agg, E);
        k_node3<<<nblkN, TPB, 0, stream>>>(b2, W3, fdinv, agg, xw3, agg3, N);
        k_prop2<<<nblkE, TPB, 0, stream>>>(row, col, fdinv, xw3, agg3, E);
        k_out<<<nblkN, TPB, 0, stream>>>(b3, Wc, bc, agg3, out, y3out, N);
    }
}

// Round 14
// 219.782 us; speedup vs baseline: 1.2957x; 1.2957x over previous
//
#include <hip/hip_runtime.h>
#include <stdint.h>

#define TPB 256
#define SPAN 512        // nodes per dest bucket (bucket = col>>9)
#define LSH 9           // log2(SPAN)
#define HSPAN 256       // nodes per sort half-bucket
#define PART_B 256      // partition blocks (one per CU)
#define PART_T 1024     // threads in hist/partition/sort kernels
#define SCAN_T 1024
#define SCAN_B 4096     // elements per scan block (1024 thr x 4)
#define HCAP 17408      // words of dynamic LDS (68KB); half-window ~16326±128 (+8.5sigma)

// ---------------------------------------------------------------------------
// GCN 3-layer forward on MI355X.
// R14: R12 pipeline with the occupancy lesson from R13's failure (persistent
// mega-kernel: 1 blk/CU on 196 CUs = 0.38x thread parallelism -> latency-
// bound gathers 2.6x slower). Changes vs R12:
// (1) p_sort -> p_sort_h: one block per HALF-bucket (grid 392, 256 nodes
//     each). 68KB dyn + 8KB static = 76KB LDS -> 2 blocks/CU, 32 waves/CU,
//     full chip. Full-window hist (needed for indptr base), sort own half
//     into LDS, coalesced csr writeout of own contiguous range.
// (2) xw1d fused into p_sort_h tail (wave/node over own 256 nodes, dinv
//     from LDS hist) - kernel + dinv round-trip deleted.
// p_hist/scan/p_part unchanged (p_part: 512B runs, amp 1.1 proven R12).
// Gathers unchanged (full occupancy). R3 atomic-push fallback kept.
// agg[c] = dinv[c]*(sum_in dxw[r] + dxw[c]), dxw = dinv*(h@W).
// ---------------------------------------------------------------------------

// ---------------- bucket partition (unchanged from R12) ----------------

__global__ __launch_bounds__(PART_T) void p_hist(
    const int* __restrict__ col, uint32_t* __restrict__ H,
    int NB, int E, int PBE) {
    __shared__ uint32_t cnt[1024];
    for (int i = threadIdx.x; i < NB; i += PART_T) cnt[i] = 0u;
    __syncthreads();
    int blk = blockIdx.x;
    int s = blk * PBE, e = min(E, s + PBE);
    for (int i = s + threadIdx.x; i < e; i += PART_T)
        atomicAdd(&cnt[col[i] >> LSH], 1u);
    __syncthreads();
    for (int i = threadIdx.x; i < NB; i += PART_T)
        H[(size_t)i * PART_B + blk] = cnt[i];
}

__global__ __launch_bounds__(SCAN_T) void k_scan1(
    const unsigned int* __restrict__ in, unsigned int* __restrict__ partial,
    unsigned int* __restrict__ bsum, int M) {
    __shared__ unsigned int sm[SCAN_T];
    int tid  = threadIdx.x;
    int base = blockIdx.x * SCAN_B + tid * 4;
    unsigned int v0 = (base + 0 < M) ? in[base + 0] : 0u;
    unsigned int v1 = (base + 1 < M) ? in[base + 1] : 0u;
    unsigned int v2 = (base + 2 < M) ? in[base + 2] : 0u;
    unsigned int v3 = (base + 3 < M) ? in[base + 3] : 0u;
    unsigned int s = v0 + v1 + v2 + v3;
    sm[tid] = s;
    __syncthreads();
    for (int off = 1; off < SCAN_T; off <<= 1) {
        unsigned int t = (tid >= off) ? sm[tid - off] : 0u;
        __syncthreads();
        sm[tid] += t;
        __syncthreads();
    }
    unsigned int excl = sm[tid] - s;
    if (base + 0 < M) partial[base + 0] = excl;
    if (base + 1 < M) partial[base + 1] = excl + v0;
    if (base + 2 < M) partial[base + 2] = excl + v0 + v1;
    if (base + 3 < M) partial[base + 3] = excl + v0 + v1 + v2;
    if (tid == SCAN_T - 1) bsum[blockIdx.x] = sm[SCAN_T - 1];
}

__global__ void k_scan2(unsigned int* __restrict__ bsum, int nb) {
    if (threadIdx.x == 0 && blockIdx.x == 0) {
        unsigned int run = 0;
        for (int i = 0; i < nb; ++i) {
            unsigned int t = bsum[i];
            bsum[i] = run;
            run += t;
        }
    }
}

__global__ __launch_bounds__(TPB) void k_scan3(
    const unsigned int* __restrict__ partial, const unsigned int* __restrict__ bsum,
    unsigned int* __restrict__ outp, int M, int E) {
    int i = blockIdx.x * TPB + threadIdx.x;
    if (i < M) outp[i] = partial[i] + bsum[i / SCAN_B];
    if (i == 0) outp[M] = (unsigned int)E;
}

__global__ __launch_bounds__(PART_T) void p_part(
    const int* __restrict__ row, const int* __restrict__ col,
    const uint32_t* __restrict__ O, uint32_t* __restrict__ bpack,
    int NB, int E, int PBE) {
    __shared__ uint32_t cur[1024];
    int blk = blockIdx.x;
    for (int i = threadIdx.x; i < NB; i += PART_T)
        cur[i] = O[(size_t)i * PART_B + blk];
    __syncthreads();
    int s = blk * PBE, e = min(E, s + PBE);
    for (int i = s + threadIdx.x; i < e; i += PART_T) {
        int c = col[i];
        uint32_t slot = atomicAdd(&cur[c >> LSH], 1u);
        bpack[slot] = ((uint32_t)row[i] << LSH) | (uint32_t)(c & (SPAN - 1));
    }
}

// Half-bucket counting sort + fused dxw1. Block j: bucket j>>1, half j&1.
// Full-window hist (both halves) -> indptr/dinv for own 256 nodes; sort own
// half into LDS; coalesced csr writeout of own contiguous range; then
// dxw1 = dinv * (x @ W1) for own nodes (wave per node).
extern __shared__ uint32_t sort_buf[];  // HCAP words
__global__ __launch_bounds__(PART_T) void p_sort_h(
    const uint32_t* __restrict__ bpack, const uint32_t* __restrict__ O,
    const float* __restrict__ x, const float* __restrict__ W1,
    int* __restrict__ csr_row, unsigned int* __restrict__ indptr,
    float* __restrict__ dinv, float* __restrict__ dxw1,
    int NB, int N, int E) {
    __shared__ uint32_t hist[SPAN];
    __shared__ uint32_t cur[SPAN];
    __shared__ uint32_t starts[SPAN + 1];
    __shared__ float    sW1[512];
    int j = blockIdx.x;
    int b = j >> 1, half = j & 1;
    int t = threadIdx.x;
    if (t < 512) sW1[t] = W1[t];
    if (t < SPAN) hist[t] = 0u;
    __syncthreads();
    uint32_t s = O[(size_t)b * PART_B];
    uint32_t e = O[(size_t)(b + 1) * PART_B];  // b+1==NB -> O[M]==E sentinel
    for (uint32_t i = s + t; i < e; i += PART_T)
        atomicAdd(&hist[bpack[i] & (SPAN - 1)], 1u);
    __syncthreads();
    if (t < SPAN) cur[t] = hist[t];
    __syncthreads();
    for (int off = 1; off < SPAN; off <<= 1) {  // Hillis-Steele inclusive scan
        uint32_t v = (t < SPAN && t >= off) ? cur[t - off] : 0u;
        __syncthreads();
        if (t < SPAN) cur[t] += v;
        __syncthreads();
    }
    if (t < SPAN) starts[t] = cur[t] - hist[t];
    if (t == 0) starts[SPAN] = e - s;
    __syncthreads();
    uint32_t hbase = starts[half * HSPAN];                  // window-relative
    uint32_t Wh    = starts[(half + 1) * HSPAN] - hbase;    // own-half size
    if (t < HSPAN) {
        int ld = half * HSPAN + t;
        int n  = b * SPAN + ld;
        if (n < N) {
            indptr[n] = s + starts[ld];
            dinv[n]   = rsqrtf((float)(hist[ld] + 1u));  // +1 = self loop
            if (n == N - 1) indptr[N] = (unsigned int)E;
        }
    }
    if (t < SPAN) cur[t] = starts[t] - hbase;  // half-local cursor (own half valid)
    __syncthreads();
    if (Wh <= (uint32_t)HCAP) {
        for (uint32_t i = s + t; i < e; i += PART_T) {
            uint32_t v  = bpack[i];
            uint32_t ld = v & (SPAN - 1);
            if ((int)(ld >> 8) != half) continue;
            uint32_t slot = atomicAdd(&cur[ld], 1u);
            sort_buf[slot] = v >> LSH;
        }
        __syncthreads();
        for (uint32_t k = t; k < Wh; k += PART_T)
            csr_row[s + hbase + k] = (int)sort_buf[k];
    } else {
        // statistical fallback (+8.5sigma): direct scattered stores
        for (uint32_t i = s + t; i < e; i += PART_T) {
            uint32_t v  = bpack[i];
            uint32_t ld = v & (SPAN - 1);
            if ((int)(ld >> 8) != half) continue;
            uint32_t slot = atomicAdd(&cur[ld], 1u);
            csr_row[s + hbase + slot] = (int)(v >> LSH);
        }
    }
    __syncthreads();
    // fused dxw1 for own 256 nodes: wave per node
    int wid = t >> 6, lane = t & 63;
    for (int q = wid; q < HSPAN; q += (PART_T >> 6)) {
        int ld = half * HSPAN + q;
        int n  = b * SPAN + ld;
        if (n >= N) break;
        float2 v = *(const float2*)(x + (size_t)n * 128 + 2 * lane);
        const float* w0 = &sW1[(2 * lane) * 4];
        const float* w1 = &sW1[(2 * lane + 1) * 4];
        float a[4];
#pragma unroll
        for (int jj = 0; jj < 4; ++jj) a[jj] = v.x * w0[jj] + v.y * w1[jj];
#pragma unroll
        for (int off = 32; off > 0; off >>= 1) {
#pragma unroll
            for (int jj = 0; jj < 4; ++jj) a[jj] += __shfl_down(a[jj], off);
        }
        if (lane == 0) {
            float d = rsqrtf((float)(hist[ld] + 1u));
            *(float4*)(dxw1 + (size_t)n * 4) =
                make_float4(d * a[0], d * a[1], d * a[2], d * a[3]);
        }
    }
}

// ---------------- gather kernels (unchanged from R12) ----------------

__global__ __launch_bounds__(TPB) void k_gather44(
    const unsigned int* __restrict__ indptr, const int* __restrict__ csr_row,
    const float* __restrict__ dinv, const float* __restrict__ dxw_in,
    const float* __restrict__ b, const float* __restrict__ W,
    float* __restrict__ dxw_out, int N) {
    int gid  = blockIdx.x * TPB + threadIdx.x;
    int node = gid >> 4;
    int sub  = gid & 15;
    if (node >= N) return;
    int e0 = (int)indptr[node], e1 = (int)indptr[node + 1];
    float4 acc = make_float4(0.f, 0.f, 0.f, 0.f);
    for (int j = e0 + sub; j < e1; j += 16) {
        int r = csr_row[j];
        float4 m = *(const float4*)(dxw_in + (size_t)r * 4);
        acc.x += m.x; acc.y += m.y; acc.z += m.z; acc.w += m.w;
    }
#pragma unroll
    for (int off = 1; off < 16; off <<= 1) {
        acc.x += __shfl_xor(acc.x, off);
        acc.y += __shfl_xor(acc.y, off);
        acc.z += __shfl_xor(acc.z, off);
        acc.w += __shfl_xor(acc.w, off);
    }
    if (sub == 0) {
        float d = dinv[node];
        float4 sv = *(const float4*)(dxw_in + (size_t)node * 4);
        float h0 = fmaxf(d * (acc.x + sv.x) + b[0], 0.f);
        float h1 = fmaxf(d * (acc.y + sv.y) + b[1], 0.f);
        float h2 = fmaxf(d * (acc.z + sv.z) + b[2], 0.f);
        float h3 = fmaxf(d * (acc.w + sv.w) + b[3], 0.f);
        float o[4];
#pragma unroll
        for (int j = 0; j < 4; ++j)
            o[j] = h0 * W[0 * 4 + j] + h1 * W[1 * 4 + j] +
                   h2 * W[2 * 4 + j] + h3 * W[3 * 4 + j];
        *(float4*)(dxw_out + (size_t)node * 4) =
            make_float4(d * o[0], d * o[1], d * o[2], d * o[3]);
    }
}

__global__ __launch_bounds__(TPB) void k_gather42(
    const unsigned int* __restrict__ indptr, const int* __restrict__ csr_row,
    const float* __restrict__ dinv, const float* __restrict__ dxw_in,
    const float* __restrict__ b, const float* __restrict__ W,
    float* __restrict__ dxw_out, int N) {
    int gid  = blockIdx.x * TPB + threadIdx.x;
    int node = gid >> 4;
    int sub  = gid & 15;
    if (node >= N) return;
    int e0 = (int)indptr[node], e1 = (int)indptr[node + 1];
    float4 acc = make_float4(0.f, 0.f, 0.f, 0.f);
    for (int j = e0 + sub; j < e1; j += 16) {
        int r = csr_row[j];
        float4 m = *(const float4*)(dxw_in + (size_t)r * 4);
        acc.x += m.x; acc.y += m.y; acc.z += m.z; acc.w += m.w;
    }
#pragma unroll
    for (int off = 1; off < 16; off <<= 1) {
        acc.x += __shfl_xor(acc.x, off);
        acc.y += __shfl_xor(acc.y, off);
        acc.z += __shfl_xor(acc.z, off);
        acc.w += __shfl_xor(acc.w, off);
    }
    if (sub == 0) {
        float d = dinv[node];
        float4 sv = *(const float4*)(dxw_in + (size_t)node * 4);
        float h0 = fmaxf(d * (acc.x + sv.x) + b[0], 0.f);
        float h1 = fmaxf(d * (acc.y + sv.y) + b[1], 0.f);
        float h2 = fmaxf(d * (acc.z + sv.z) + b[2], 0.f);
        float h3 = fmaxf(d * (acc.w + sv.w) + b[3], 0.f);
        float o0 = h0 * W[0] + h1 * W[2] + h2 * W[4] + h3 * W[6];
        float o1 = h0 * W[1] + h1 * W[3] + h2 * W[5] + h3 * W[7];
        *(float2*)(dxw_out + (size_t)node * 2) = make_float2(d * o0, d * o1);
    }
}

__global__ __launch_bounds__(TPB) void k_gather2out(
    const unsigned int* __restrict__ indptr, const int* __restrict__ csr_row,
    const float* __restrict__ dinv, const float* __restrict__ dxw3,
    const float* __restrict__ b3, const float* __restrict__ Wc,
    const float* __restrict__ bc,
    float* __restrict__ out, float* __restrict__ y3out, int N) {
    int gid  = blockIdx.x * TPB + threadIdx.x;
    int node = gid >> 4;
    int sub  = gid & 15;
    if (node >= N) return;
    int e0 = (int)indptr[node], e1 = (int)indptr[node + 1];
    float ax = 0.f, ay = 0.f;
    for (int j = e0 + sub; j < e1; j += 16) {
        int r = csr_row[j];
        float2 m = *(const float2*)(dxw3 + (size_t)r * 2);
        ax += m.x; ay += m.y;
    }
#pragma unroll
    for (int off = 1; off < 16; off <<= 1) {
        ax += __shfl_xor(ax, off);
        ay += __shfl_xor(ay, off);
    }
    if (sub == 0) {
        float d = dinv[node];
        float2 sv = *(const float2*)(dxw3 + (size_t)node * 2);
        float y0 = fmaxf(d * (ax + sv.x) + b3[0], 0.f);
        float y1 = fmaxf(d * (ay + sv.y) + b3[1], 0.f);
        float o[4];
#pragma unroll
        for (int j = 0; j < 4; ++j)
            o[j] = y0 * Wc[0 * 4 + j] + y1 * Wc[1 * 4 + j] + bc[j];
        *(float4*)(out + (size_t)node * 4) = make_float4(o[0], o[1], o[2], o[3]);
        *(float2*)(y3out + (size_t)node * 2) = make_float2(y0, y1);
    }
}

// ---------------- R3 fallback kernels (atomic push path) ----------------

__global__ __launch_bounds__(TPB) void k_zero_deg(unsigned int* __restrict__ deg, int N) {
    int i = blockIdx.x * TPB + threadIdx.x;
    if (i < N) deg[i] = 0u;
}

__global__ __launch_bounds__(TPB) void k_deg(
    const int* __restrict__ col, unsigned int* __restrict__ deg, int E) {
    int e = blockIdx.x * TPB + threadIdx.x;
    if (e >= E) return;
    atomicAdd(&deg[col[e]], 1u);
}

__global__ __launch_bounds__(TPB) void k_dinv(const unsigned int* __restrict__ deg,
                                              float* __restrict__ dinv, int N) {
    int i = blockIdx.x * TPB + threadIdx.x;
    if (i < N) dinv[i] = rsqrtf((float)(deg[i] + 1u));
}

__global__ __launch_bounds__(TPB) void k_xw1(
    const float* __restrict__ x, const float* __restrict__ W1,
    const float* __restrict__ dinv,
    float* __restrict__ xw, float* __restrict__ agg, int N) {
    __shared__ float sW[512];
    for (int t = threadIdx.x; t < 512; t += TPB) sW[t] = W1[t];
    __syncthreads();
    int gid  = blockIdx.x * TPB + threadIdx.x;
    int node = gid >> 6;
    int lane = threadIdx.x & 63;
    if (node >= N) return;
    float2 v = *(const float2*)(x + (size_t)node * 128 + 2 * lane);
    const float* w0 = &sW[(2 * lane) * 4];
    const float* w1 = &sW[(2 * lane + 1) * 4];
    float a[4];
#pragma unroll
    for (int j = 0; j < 4; ++j) a[j] = v.x * w0[j] + v.y * w1[j];
#pragma unroll
    for (int off = 32; off > 0; off >>= 1) {
#pragma unroll
        for (int j = 0; j < 4; ++j) a[j] += __shfl_down(a[j], off);
    }
    if (lane == 0) {
        float d  = dinv[node];
        float d2 = d * d;
        *(float4*)(xw  + (size_t)node * 4) = make_float4(a[0], a[1], a[2], a[3]);
        *(float4*)(agg + (size_t)node * 4) =
            make_float4(d2 * a[0], d2 * a[1], d2 * a[2], d2 * a[3]);
    }
}

__global__ __launch_bounds__(TPB) void k_prop4(
    const int* __restrict__ row, const int* __restrict__ col,
    const float* __restrict__ dinv,
    const float* __restrict__ xw, float* __restrict__ agg, int E) {
    int e = blockIdx.x * TPB + threadIdx.x;
    if (e >= E) return;
    int r = row[e];
    int c = col[e];
    float nv = dinv[r] * dinv[c];
    float4 m = *(const float4*)(xw + (size_t)r * 4);
    float* a = agg + (size_t)c * 4;
    atomicAdd(a + 0, nv * m.x);
    atomicAdd(a + 1, nv * m.y);
    atomicAdd(a + 2, nv * m.z);
    atomicAdd(a + 3, nv * m.w);
}

__global__ __launch_bounds__(TPB) void k_prop2(
    const int* __restrict__ row, const int* __restrict__ col,
    const float* __restrict__ dinv,
    const float* __restrict__ xw2, float* __restrict__ agg2, int E) {
    int e = blockIdx.x * TPB + threadIdx.x;
    if (e >= E) return;
    int r = row[e];
    int c = col[e];
    float nv = dinv[r] * dinv[c];
    float2 m = *(const float2*)(xw2 + (size_t)r * 2);
    float* a = agg2 + (size_t)c * 2;
    atomicAdd(a + 0, nv * m.x);
    atomicAdd(a + 1, nv * m.y);
}

__global__ __launch_bounds__(TPB) void k_node2(
    const float* __restrict__ b1, const float* __restrict__ W2,
    const float* __restrict__ dinv,
    float* __restrict__ xw, float* __restrict__ agg, int N) {
    int i = blockIdx.x * TPB + threadIdx.x;
    if (i >= N) return;
    float4 av = *(const float4*)(agg + (size_t)i * 4);
    float h0 = fmaxf(av.x + b1[0], 0.f);
    float h1 = fmaxf(av.y + b1[1], 0.f);
    float h2 = fmaxf(av.z + b1[2], 0.f);
    float h3 = fmaxf(av.w + b1[3], 0.f);
    float o[4];
#pragma unroll
    for (int j = 0; j < 4; ++j)
        o[j] = h0 * W2[0 * 4 + j] + h1 * W2[1 * 4 + j] +
               h2 * W2[2 * 4 + j] + h3 * W2[3 * 4 + j];
    float d  = dinv[i];
    float d2 = d * d;
    *(float4*)(xw  + (size_t)i * 4) = make_float4(o[0], o[1], o[2], o[3]);
    *(float4*)(agg + (size_t)i * 4) = make_float4(d2 * o[0], d2 * o[1], d2 * o[2], d2 * o[3]);
}

__global__ __launch_bounds__(TPB) void k_node3(
    const float* __restrict__ b2, const float* __restrict__ W3,
    const float* __restrict__ dinv,
    const float* __restrict__ agg,
    float* __restrict__ xw3, float* __restrict__ agg3, int N) {
    int i = blockIdx.x * TPB + threadIdx.x;
    if (i >= N) return;
    float4 av = *(const float4*)(agg + (size_t)i * 4);
    float h0 = fmaxf(av.x + b2[0], 0.f);
    float h1 = fmaxf(av.y + b2[1], 0.f);
    float h2 = fmaxf(av.z + b2[2], 0.f);
    float h3 = fmaxf(av.w + b2[3], 0.f);
    float o0 = h0 * W3[0] + h1 * W3[2] + h2 * W3[4] + h3 * W3[6];
    float o1 = h0 * W3[1] + h1 * W3[3] + h2 * W3[5] + h3 * W3[7];
    float d  = dinv[i];
    float d2 = d * d;
    *(float2*)(xw3  + (size_t)i * 2) = make_float2(o0, o1);
    *(float2*)(agg3 + (size_t)i * 2) = make_float2(d2 * o0, d2 * o1);
}

__global__ __launch_bounds__(TPB) void k_out(
    const float* __restrict__ b3, const float* __restrict__ Wc,
    const float* __restrict__ bc,
    const float* __restrict__ agg3,
    float* __restrict__ out, float* __restrict__ y3out, int N) {
    int i = blockIdx.x * TPB + threadIdx.x;
    if (i >= N) return;
    float2 av = *(const float2*)(agg3 + (size_t)i * 2);
    float y0 = fmaxf(av.x + b3[0], 0.f);
    float y1 = fmaxf(av.y + b3[1], 0.f);
    float o[4];
#pragma unroll
    for (int j = 0; j < 4; ++j)
        o[j] = y0 * Wc[0 * 4 + j] + y1 * Wc[1 * 4 + j] + bc[j];
    *(float4*)(out + (size_t)i * 4) = make_float4(o[0], o[1], o[2], o[3]);
    *(float2*)(y3out + (size_t)i * 2) = make_float2(y0, y1);
}

extern "C" void kernel_launch(void* const* d_in, const int* in_sizes, int n_in,
                              void* d_out, int out_size, void* d_ws, size_t ws_size,
                              hipStream_t stream) {
    const float* x  = (const float*)d_in[0];
    const int*   ei = (const int*)d_in[1];   // int32 (harness converts integer inputs)
    const float* W1 = (const float*)d_in[2];
    const float* b1 = (const float*)d_in[3];
    const float* W2 = (const float*)d_in[4];
    const float* b2 = (const float*)d_in[5];
    const float* W3 = (const float*)d_in[6];
    const float* b3 = (const float*)d_in[7];
    const float* Wc = (const float*)d_in[8];
    const float* bc = (const float*)d_in[9];

    const int N = in_sizes[0] / 128;
    const int E = in_sizes[1] / 2;

    const int* row = ei;
    const int* col = ei + (size_t)E;

    const int NB  = (N + SPAN - 1) / SPAN;        // dest buckets (196)
    const int M   = NB * PART_B;                  // flattened hist size (~50K)
    const int PBE = (E + PART_B - 1) / PART_B;    // edges per partition block

    float* out   = (float*)d_out;                  // [N,4]
    float* y3out = (float*)d_out + (size_t)N * 4;  // [N,2]

    const int nblkN = (N + TPB - 1) / TPB;
    const int nblkE = (E + TPB - 1) / TPB;
    const int nblkW = (N * 64 + TPB - 1) / TPB;
    const int nblkG = (N * 16 + TPB - 1) / TPB;    // 16 threads/node
    const int nblkM = (M + 1 + TPB - 1) / TPB;
    const int nblkS = (M + SCAN_B - 1) / SCAN_B;

    // Carve (~56.2MB). H is scanned in place (becomes O).
    size_t off = 0;
    auto carve = [&](size_t bytes) -> void* {
        void* r = (void*)((char*)d_ws + off);
        off += (bytes + 255) & ~(size_t)255;
        return r;
    };
    float*        dinv    = (float*)carve((size_t)N * 4);
    float*        dxw1    = (float*)carve((size_t)N * 4 * 4);
    float*        dxw2    = (float*)carve((size_t)N * 4 * 4);
    float*        dxw3    = (float*)carve((size_t)N * 2 * 4);
    unsigned int* indptr  = (unsigned int*)carve(((size_t)N + 1) * 4);
    uint32_t*     bsum    = (uint32_t*)carve(260 * 4);
    uint32_t*     H       = (uint32_t*)carve(((size_t)M + 1) * 4);  // -> O in place
    uint32_t*     bpack   = (uint32_t*)carve((size_t)E * 4);
    int*          csr_row = (int*)carve((size_t)E * 4);
    bool use_bucket = (off <= ws_size) && (NB <= 1024) && (N < (1 << 23));

    if (use_bucket) {
        size_t sort_lds = (size_t)HCAP * 4;  // 68KB dynamic (+~8KB static)
        hipFuncSetAttribute((const void*)p_sort_h,
                            hipFuncAttributeMaxDynamicSharedMemorySize,
                            (int)sort_lds);
        p_hist<<<PART_B, PART_T, 0, stream>>>(col, H, NB, E, PBE);
        k_scan1<<<nblkS, SCAN_T, 0, stream>>>(H, H, bsum, M);         // in-place
        k_scan2<<<1, 32, 0, stream>>>(bsum, nblkS);
        k_scan3<<<nblkM, TPB, 0, stream>>>(H, bsum, H, M, E);         // in-place
        p_part<<<PART_B, PART_T, 0, stream>>>(row, col, H, bpack, NB, E, PBE);
        p_sort_h<<<2 * NB, PART_T, sort_lds, stream>>>(bpack, H, x, W1,
                                                       csr_row, indptr, dinv,
                                                       dxw1, NB, N, E);
        k_gather44<<<nblkG, TPB, 0, stream>>>(indptr, csr_row, dinv, dxw1, b1, W2, dxw2, N);
        k_gather42<<<nblkG, TPB, 0, stream>>>(indptr, csr_row, dinv, dxw2, b2, W3, dxw3, N);
        k_gather2out<<<nblkG, TPB, 0, stream>>>(indptr, csr_row, dinv, dxw3, b3, Wc, bc,
                                                out, y3out, N);
    } else {
        // R3 verified atomic-push fallback: recarve from base (~6MB).
        size_t foff = 0;
        auto fcarve = [&](size_t bytes) -> void* {
            void* r = (void*)((char*)d_ws + foff);
            foff += (bytes + 255) & ~(size_t)255;
            return r;
        };
        unsigned int* deg   = (unsigned int*)fcarve((size_t)N * 4);
        float*        fdinv = (float*)fcarve((size_t)N * 4);
        float*        xw    = (float*)fcarve((size_t)N * 4 * 4);
        float*        agg   = (float*)fcarve((size_t)N * 4 * 4);
        float*        xw3   = (float*)fcarve((size_t)N * 2 * 4);
        float*        agg3  = (float*)fcarve((size_t)N * 2 * 4);
        k_zero_deg<<<nblkN, TPB, 0, stream>>>(deg, N);
        k_deg<<<nblkE, TPB, 0, stream>>>(col, deg, E);
        k_dinv<<<nblkN, TPB, 0, stream>>>(deg, fdinv, N);
        k_xw1<<<nblkW, TPB, 0, stream>>>(x, W1, fdinv, xw, agg, N);
        k_prop4<<<nblkE, TPB, 0, stream>>>(row, col, fdinv, xw, agg, E);
        k_node2<<<nblkN, TPB, 0, stream>>>(b1, W2, fdinv, xw, agg, N);
        k_prop4<<<nblkE, TPB, 0, stream>>>(row, col, fdinv, xw, agg, E);
        k_node3<<<nblkN, TPB, 0, stream>>>(b2, W3, fdinv, agg, xw3, agg3, N);
        k_prop2<<<nblkE, TPB, 0, stream>>>(row, col, fdinv, xw3, agg3, E);
        k_out<<<nblkN, TPB, 0, stream>>>(b3, Wc, bc, agg3, out, y3out, N);
    }
}

// Round 15
// 215.520 us; speedup vs baseline: 1.3214x; 1.0198x over previous
//
#include <hip/hip_runtime.h>
#include <stdint.h>

#define TPB 256
#define SPAN 512        // nodes per dest bucket (bucket = col>>9)
#define LSH 9           // log2(SPAN)
#define PART_B 256      // partition blocks (one per CU)
#define PART_T 1024     // threads in hist/partition/sort kernels
#define SCAN_T 1024
#define SCAN_B 4096     // elements per scan block (1024 thr x 4)
#define SORT_CAP 35840  // words of dynamic LDS sort buffer (140KB); W ~32653±181

// ---------------------------------------------------------------------------
// GCN 3-layer forward on MI355X.
// R15 = R12 (best verified, 208.6us) + xw1d fused into p_sort tail.
// R14's regression was the HALF-split double-read (each half-block read the
// full window twice, FETCH 75MB), NOT the fusion - fusion verified correct.
// Here p_sort keeps R12's full-bucket geometry (196 blocks, 144KB LDS) and
// appends the wave-per-node dxw1 = dinv*(x@W1) tail using the LDS hist it
// already built (dinv free). Deletes xw1d kernel + dinv round-trip.
// Pipeline: p_hist | scan(in place) | p_part (512B runs, amp 1.1 proven) |
// p_sort(+xw1 tail) | 3x CSR gather (full occupancy).
// agg[c] = dinv[c]*(sum_in dxw[r] + dxw[c]), dxw = dinv*(h@W).
// WS ~56.2MB. R3 atomic-push fallback kept.
// ---------------------------------------------------------------------------

// ---------------- bucket partition (unchanged from R12) ----------------

__global__ __launch_bounds__(PART_T) void p_hist(
    const int* __restrict__ col, uint32_t* __restrict__ H,
    int NB, int E, int PBE) {
    __shared__ uint32_t cnt[1024];
    for (int i = threadIdx.x; i < NB; i += PART_T) cnt[i] = 0u;
    __syncthreads();
    int blk = blockIdx.x;
    int s = blk * PBE, e = min(E, s + PBE);
    for (int i = s + threadIdx.x; i < e; i += PART_T)
        atomicAdd(&cnt[col[i] >> LSH], 1u);
    __syncthreads();
    for (int i = threadIdx.x; i < NB; i += PART_T)
        H[(size_t)i * PART_B + blk] = cnt[i];
}

__global__ __launch_bounds__(SCAN_T) void k_scan1(
    const unsigned int* __restrict__ in, unsigned int* __restrict__ partial,
    unsigned int* __restrict__ bsum, int M) {
    __shared__ unsigned int sm[SCAN_T];
    int tid  = threadIdx.x;
    int base = blockIdx.x * SCAN_B + tid * 4;
    unsigned int v0 = (base + 0 < M) ? in[base + 0] : 0u;
    unsigned int v1 = (base + 1 < M) ? in[base + 1] : 0u;
    unsigned int v2 = (base + 2 < M) ? in[base + 2] : 0u;
    unsigned int v3 = (base + 3 < M) ? in[base + 3] : 0u;
    unsigned int s = v0 + v1 + v2 + v3;
    sm[tid] = s;
    __syncthreads();
    for (int off = 1; off < SCAN_T; off <<= 1) {
        unsigned int t = (tid >= off) ? sm[tid - off] : 0u;
        __syncthreads();
        sm[tid] += t;
        __syncthreads();
    }
    unsigned int excl = sm[tid] - s;
    if (base + 0 < M) partial[base + 0] = excl;
    if (base + 1 < M) partial[base + 1] = excl + v0;
    if (base + 2 < M) partial[base + 2] = excl + v0 + v1;
    if (base + 3 < M) partial[base + 3] = excl + v0 + v1 + v2;
    if (tid == SCAN_T - 1) bsum[blockIdx.x] = sm[SCAN_T - 1];
}

__global__ void k_scan2(unsigned int* __restrict__ bsum, int nb) {
    if (threadIdx.x == 0 && blockIdx.x == 0) {
        unsigned int run = 0;
        for (int i = 0; i < nb; ++i) {
            unsigned int t = bsum[i];
            bsum[i] = run;
            run += t;
        }
    }
}

__global__ __launch_bounds__(TPB) void k_scan3(
    const unsigned int* __restrict__ partial, const unsigned int* __restrict__ bsum,
    unsigned int* __restrict__ outp, int M, int E) {
    int i = blockIdx.x * TPB + threadIdx.x;
    if (i < M) outp[i] = partial[i] + bsum[i / SCAN_B];
    if (i == 0) outp[M] = (unsigned int)E;
}

__global__ __launch_bounds__(PART_T) void p_part(
    const int* __restrict__ row, const int* __restrict__ col,
    const uint32_t* __restrict__ O, uint32_t* __restrict__ bpack,
    int NB, int E, int PBE) {
    __shared__ uint32_t cur[1024];
    int blk = blockIdx.x;
    for (int i = threadIdx.x; i < NB; i += PART_T)
        cur[i] = O[(size_t)i * PART_B + blk];
    __syncthreads();
    int s = blk * PBE, e = min(E, s + PBE);
    for (int i = s + threadIdx.x; i < e; i += PART_T) {
        int c = col[i];
        uint32_t slot = atomicAdd(&cur[c >> LSH], 1u);
        bpack[slot] = ((uint32_t)row[i] << LSH) | (uint32_t)(c & (SPAN - 1));
    }
}

// Per-bucket counting sort (512-node buckets, R12 geometry) + fused xw1
// tail. LDS staging (140KB dynamic), coalesced csr writeout, emits indptr
// + dinv, then dxw1 = dinv * (x @ W1) for own 512 nodes (wave per node).
extern __shared__ uint32_t sort_buf[];
__global__ __launch_bounds__(PART_T) void p_sort(
    const uint32_t* __restrict__ bpack, const uint32_t* __restrict__ O,
    const float* __restrict__ x, const float* __restrict__ W1,
    int* __restrict__ csr_row, unsigned int* __restrict__ indptr,
    float* __restrict__ dinv, float* __restrict__ dxw1,
    int NB, int N, int E) {
    __shared__ uint32_t hist[SPAN];
    __shared__ uint32_t cur[SPAN];
    __shared__ float    sW1[512];
    int b = blockIdx.x;
    int t = threadIdx.x;
    if (t < 512) sW1[t] = W1[t];
    if (t < SPAN) hist[t] = 0u;
    __syncthreads();
    uint32_t s = O[(size_t)b * PART_B];
    uint32_t e = O[(size_t)(b + 1) * PART_B];  // b+1==NB -> O[M]==E sentinel
    uint32_t W = e - s;
    for (uint32_t i = s + t; i < e; i += PART_T)
        atomicAdd(&hist[bpack[i] & (SPAN - 1)], 1u);
    __syncthreads();
    if (t < SPAN) cur[t] = hist[t];
    __syncthreads();
    for (int off = 1; off < SPAN; off <<= 1) {  // Hillis-Steele inclusive scan
        uint32_t v = (t < SPAN && t >= off) ? cur[t - off] : 0u;
        __syncthreads();
        if (t < SPAN) cur[t] += v;
        __syncthreads();
    }
    if (t < SPAN) {
        uint32_t excl = cur[t] - hist[t];
        int n = b * SPAN + t;
        if (n < N) {
            indptr[n] = s + excl;                      // dense: csr base == bpack base
            dinv[n]   = rsqrtf((float)(hist[t] + 1u)); // +1 = self loop
            if (n == N - 1) indptr[N] = (unsigned int)E;
        }
        cur[t] = excl;  // window-local cursor
    }
    __syncthreads();
    if (W <= SORT_CAP) {
        for (uint32_t i = s + t; i < e; i += PART_T) {
            uint32_t v = bpack[i];
            uint32_t slot = atomicAdd(&cur[v & (SPAN - 1)], 1u);
            sort_buf[slot] = v >> LSH;
        }
        __syncthreads();
        for (uint32_t j = t; j < W; j += PART_T)
            csr_row[s + j] = (int)sort_buf[j];
    } else {
        // statistical fallback (+17sigma): direct scattered stores
        for (uint32_t i = s + t; i < e; i += PART_T) {
            uint32_t v = bpack[i];
            uint32_t slot = atomicAdd(&cur[v & (SPAN - 1)], 1u);
            csr_row[s + slot] = (int)(v >> LSH);
        }
    }
    __syncthreads();
    // fused xw1 tail: dxw1 = dinv * (x @ W1), wave per node over own 512.
    int wid = t >> 6, lane = t & 63;
    for (int ld = wid; ld < SPAN; ld += (PART_T >> 6)) {
        int n = b * SPAN + ld;
        if (n >= N) break;
        float2 v = *(const float2*)(x + (size_t)n * 128 + 2 * lane);
        const float* w0 = &sW1[(2 * lane) * 4];
        const float* w1 = &sW1[(2 * lane + 1) * 4];
        float a[4];
#pragma unroll
        for (int j = 0; j < 4; ++j) a[j] = v.x * w0[j] + v.y * w1[j];
#pragma unroll
        for (int off = 32; off > 0; off >>= 1) {
#pragma unroll
            for (int j = 0; j < 4; ++j) a[j] += __shfl_down(a[j], off);
        }
        if (lane == 0) {
            float d = rsqrtf((float)(hist[ld] + 1u));
            *(float4*)(dxw1 + (size_t)n * 4) =
                make_float4(d * a[0], d * a[1], d * a[2], d * a[3]);
        }
    }
}

// ---------------- gather kernels (unchanged from R12) ----------------

__global__ __launch_bounds__(TPB) void k_gather44(
    const unsigned int* __restrict__ indptr, const int* __restrict__ csr_row,
    const float* __restrict__ dinv, const float* __restrict__ dxw_in,
    const float* __restrict__ b, const float* __restrict__ W,
    float* __restrict__ dxw_out, int N) {
    int gid  = blockIdx.x * TPB + threadIdx.x;
    int node = gid >> 4;
    int sub  = gid & 15;
    if (node >= N) return;
    int e0 = (int)indptr[node], e1 = (int)indptr[node + 1];
    float4 acc = make_float4(0.f, 0.f, 0.f, 0.f);
    for (int j = e0 + sub; j < e1; j += 16) {
        int r = csr_row[j];
        float4 m = *(const float4*)(dxw_in + (size_t)r * 4);
        acc.x += m.x; acc.y += m.y; acc.z += m.z; acc.w += m.w;
    }
#pragma unroll
    for (int off = 1; off < 16; off <<= 1) {
        acc.x += __shfl_xor(acc.x, off);
        acc.y += __shfl_xor(acc.y, off);
        acc.z += __shfl_xor(acc.z, off);
        acc.w += __shfl_xor(acc.w, off);
    }
    if (sub == 0) {
        float d = dinv[node];
        float4 sv = *(const float4*)(dxw_in + (size_t)node * 4);
        float h0 = fmaxf(d * (acc.x + sv.x) + b[0], 0.f);
        float h1 = fmaxf(d * (acc.y + sv.y) + b[1], 0.f);
        float h2 = fmaxf(d * (acc.z + sv.z) + b[2], 0.f);
        float h3 = fmaxf(d * (acc.w + sv.w) + b[3], 0.f);
        float o[4];
#pragma unroll
        for (int j = 0; j < 4; ++j)
            o[j] = h0 * W[0 * 4 + j] + h1 * W[1 * 4 + j] +
                   h2 * W[2 * 4 + j] + h3 * W[3 * 4 + j];
        *(float4*)(dxw_out + (size_t)node * 4) =
            make_float4(d * o[0], d * o[1], d * o[2], d * o[3]);
    }
}

__global__ __launch_bounds__(TPB) void k_gather42(
    const unsigned int* __restrict__ indptr, const int* __restrict__ csr_row,
    const float* __restrict__ dinv, const float* __restrict__ dxw_in,
    const float* __restrict__ b, const float* __restrict__ W,
    float* __restrict__ dxw_out, int N) {
    int gid  = blockIdx.x * TPB + threadIdx.x;
    int node = gid >> 4;
    int sub  = gid & 15;
    if (node >= N) return;
    int e0 = (int)indptr[node], e1 = (int)indptr[node + 1];
    float4 acc = make_float4(0.f, 0.f, 0.f, 0.f);
    for (int j = e0 + sub; j < e1; j += 16) {
        int r = csr_row[j];
        float4 m = *(const float4*)(dxw_in + (size_t)r * 4);
        acc.x += m.x; acc.y += m.y; acc.z += m.z; acc.w += m.w;
    }
#pragma unroll
    for (int off = 1; off < 16; off <<= 1) {
        acc.x += __shfl_xor(acc.x, off);
        acc.y += __shfl_xor(acc.y, off);
        acc.z += __shfl_xor(acc.z, off);
        acc.w += __shfl_xor(acc.w, off);
    }
    if (sub == 0) {
        float d = dinv[node];
        float4 sv = *(const float4*)(dxw_in + (size_t)node * 4);
        float h0 = fmaxf(d * (acc.x + sv.x) + b[0], 0.f);
        float h1 = fmaxf(d * (acc.y + sv.y) + b[1], 0.f);
        float h2 = fmaxf(d * (acc.z + sv.z) + b[2], 0.f);
        float h3 = fmaxf(d * (acc.w + sv.w) + b[3], 0.f);
        float o0 = h0 * W[0] + h1 * W[2] + h2 * W[4] + h3 * W[6];
        float o1 = h0 * W[1] + h1 * W[3] + h2 * W[5] + h3 * W[7];
        *(float2*)(dxw_out + (size_t)node * 2) = make_float2(d * o0, d * o1);
    }
}

__global__ __launch_bounds__(TPB) void k_gather2out(
    const unsigned int* __restrict__ indptr, const int* __restrict__ csr_row,
    const float* __restrict__ dinv, const float* __restrict__ dxw3,
    const float* __restrict__ b3, const float* __restrict__ Wc,
    const float* __restrict__ bc,
    float* __restrict__ out, float* __restrict__ y3out, int N) {
    int gid  = blockIdx.x * TPB + threadIdx.x;
    int node = gid >> 4;
    int sub  = gid & 15;
    if (node >= N) return;
    int e0 = (int)indptr[node], e1 = (int)indptr[node + 1];
    float ax = 0.f, ay = 0.f;
    for (int j = e0 + sub; j < e1; j += 16) {
        int r = csr_row[j];
        float2 m = *(const float2*)(dxw3 + (size_t)r * 2);
        ax += m.x; ay += m.y;
    }
#pragma unroll
    for (int off = 1; off < 16; off <<= 1) {
        ax += __shfl_xor(ax, off);
        ay += __shfl_xor(ay, off);
    }
    if (sub == 0) {
        float d = dinv[node];
        float2 sv = *(const float2*)(dxw3 + (size_t)node * 2);
        float y0 = fmaxf(d * (ax + sv.x) + b3[0], 0.f);
        float y1 = fmaxf(d * (ay + sv.y) + b3[1], 0.f);
        float o[4];
#pragma unroll
        for (int j = 0; j < 4; ++j)
            o[j] = y0 * Wc[0 * 4 + j] + y1 * Wc[1 * 4 + j] + bc[j];
        *(float4*)(out + (size_t)node * 4) = make_float4(o[0], o[1], o[2], o[3]);
        *(float2*)(y3out + (size_t)node * 2) = make_float2(y0, y1);
    }
}

// ---------------- R3 fallback kernels (atomic push path) ----------------

__global__ __launch_bounds__(TPB) void k_zero_deg(unsigned int* __restrict__ deg, int N) {
    int i = blockIdx.x * TPB + threadIdx.x;
    if (i < N) deg[i] = 0u;
}

__global__ __launch_bounds__(TPB) void k_deg(
    const int* __restrict__ col, unsigned int* __restrict__ deg, int E) {
    int e = blockIdx.x * TPB + threadIdx.x;
    if (e >= E) return;
    atomicAdd(&deg[col[e]], 1u);
}

__global__ __launch_bounds__(TPB) void k_dinv(const unsigned int* __restrict__ deg,
                                              float* __restrict__ dinv, int N) {
    int i = blockIdx.x * TPB + threadIdx.x;
    if (i < N) dinv[i] = rsqrtf((float)(deg[i] + 1u));
}

__global__ __launch_bounds__(TPB) void k_xw1(
    const float* __restrict__ x, const float* __restrict__ W1,
    const float* __restrict__ dinv,
    float* __restrict__ xw, float* __restrict__ agg, int N) {
    __shared__ float sW[512];
    for (int t = threadIdx.x; t < 512; t += TPB) sW[t] = W1[t];
    __syncthreads();
    int gid  = blockIdx.x * TPB + threadIdx.x;
    int node = gid >> 6;
    int lane = threadIdx.x & 63;
    if (node >= N) return;
    float2 v = *(const float2*)(x + (size_t)node * 128 + 2 * lane);
    const float* w0 = &sW[(2 * lane) * 4];
    const float* w1 = &sW[(2 * lane + 1) * 4];
    float a[4];
#pragma unroll
    for (int j = 0; j < 4; ++j) a[j] = v.x * w0[j] + v.y * w1[j];
#pragma unroll
    for (int off = 32; off > 0; off >>= 1) {
#pragma unroll
        for (int j = 0; j < 4; ++j) a[j] += __shfl_down(a[j], off);
    }
    if (lane == 0) {
        float d  = dinv[node];
        float d2 = d * d;
        *(float4*)(xw  + (size_t)node * 4) = make_float4(a[0], a[1], a[2], a[3]);
        *(float4*)(agg + (size_t)node * 4) =
            make_float4(d2 * a[0], d2 * a[1], d2 * a[2], d2 * a[3]);
    }
}

__global__ __launch_bounds__(TPB) void k_prop4(
    const int* __restrict__ row, const int* __restrict__ col,
    const float* __restrict__ dinv,
    const float* __restrict__ xw, float* __restrict__ agg, int E) {
    int e = blockIdx.x * TPB + threadIdx.x;
    if (e >= E) return;
    int r = row[e];
    int c = col[e];
    float nv = dinv[r] * dinv[c];
    float4 m = *(const float4*)(xw + (size_t)r * 4);
    float* a = agg + (size_t)c * 4;
    atomicAdd(a + 0, nv * m.x);
    atomicAdd(a + 1, nv * m.y);
    atomicAdd(a + 2, nv * m.z);
    atomicAdd(a + 3, nv * m.w);
}

__global__ __launch_bounds__(TPB) void k_prop2(
    const int* __restrict__ row, const int* __restrict__ col,
    const float* __restrict__ dinv,
    const float* __restrict__ xw2, float* __restrict__ agg2, int E) {
    int e = blockIdx.x * TPB + threadIdx.x;
    if (e >= E) return;
    int r = row[e];
    int c = col[e];
    float nv = dinv[r] * dinv[c];
    float2 m = *(const float2*)(xw2 + (size_t)r * 2);
    float* a = agg2 + (size_t)c * 2;
    atomicAdd(a + 0, nv * m.x);
    atomicAdd(a + 1, nv * m.y);
}

__global__ __launch_bounds__(TPB) void k_node2(
    const float* __restrict__ b1, const float* __restrict__ W2,
    const float* __restrict__ dinv,
    float* __restrict__ xw, float* __restrict__ agg, int N) {
    int i = blockIdx.x * TPB + threadIdx.x;
    if (i >= N) return;
    float4 av = *(const float4*)(agg + (size_t)i * 4);
    float h0 = fmaxf(av.x + b1[0], 0.f);
    float h1 = fmaxf(av.y + b1[1], 0.f);
    float h2 = fmaxf(av.z + b1[2], 0.f);
    float h3 = fmaxf(av.w + b1[3], 0.f);
    float o[4];
#pragma unroll
    for (int j = 0; j < 4; ++j)
        o[j] = h0 * W2[0 * 4 + j] + h1 * W2[1 * 4 + j] +
               h2 * W2[2 * 4 + j] + h3 * W2[3 * 4 + j];
    float d  = dinv[i];
    float d2 = d * d;
    *(float4*)(xw  + (size_t)i * 4) = make_float4(o[0], o[1], o[2], o[3]);
    *(float4*)(agg + (size_t)i * 4) = make_float4(d2 * o[0], d2 * o[1], d2 * o[2], d2 * o[3]);
}

__global__ __launch_bounds__(TPB) void k_node3(
    const float* __restrict__ b2, const float* __restrict__ W3,
    const float* __restrict__ dinv,
    const float* __restrict__ agg,
    float* __restrict__ xw3, float* __restrict__ agg3, int N) {
    int i = blockIdx.x * TPB + threadIdx.x;
    if (i >= N) return;
    float4 av = *(const float4*)(agg + (size_t)i * 4);
    float h0 = fmaxf(av.x + b2[0], 0.f);
    float h1 = fmaxf(av.y + b2[1], 0.f);
    float h2 = fmaxf(av.z + b2[2], 0.f);
    float h3 = fmaxf(av.w + b2[3], 0.f);
    float o0 = h0 * W3[0] + h1 * W3[2] + h2 * W3[4] + h3 * W3[6];
    float o1 = h0 * W3[1] + h1 * W3[3] + h2 * W3[5] + h3 * W3[7];
    float d  = dinv[i];
    float d2 = d * d;
    *(float2*)(xw3  + (size_t)i * 2) = make_float2(o0, o1);
    *(float2*)(agg3 + (size_t)i * 2) = make_float2(d2 * o0, d2 * o1);
}

__global__ __launch_bounds__(TPB) void k_out(
    const float* __restrict__ b3, const float* __restrict__ Wc,
    const float* __restrict__ bc,
    const float* __restrict__ agg3,
    float* __restrict__ out, float* __restrict__ y3out, int N) {
    int i = blockIdx.x * TPB + threadIdx.x;
    if (i >= N) return;
    float2 av = *(const float2*)(agg3 + (size_t)i * 2);
    float y0 = fmaxf(av.x + b3[0], 0.f);
    float y1 = fmaxf(av.y + b3[1], 0.f);
    float o[4];
#pragma unroll
    for (int j = 0; j < 4; ++j)
        o[j] = y0 * Wc[0 * 4 + j] + y1 * Wc[1 * 4 + j] + bc[j];
    *(float4*)(out + (size_t)i * 4) = make_float4(o[0], o[1], o[2], o[3]);
    *(float2*)(y3out + (size_t)i * 2) = make_float2(y0, y1);
}

extern "C" void kernel_launch(void* const* d_in, const int* in_sizes, int n_in,
                              void* d_out, int out_size, void* d_ws, size_t ws_size,
                              hipStream_t stream) {
    const float* x  = (const float*)d_in[0];
    const int*   ei = (const int*)d_in[1];   // int32 (harness converts integer inputs)
    const float* W1 = (const float*)d_in[2];
    const float* b1 = (const float*)d_in[3];
    const float* W2 = (const float*)d_in[4];
    const float* b2 = (const float*)d_in[5];
    const float* W3 = (const float*)d_in[6];
    const float* b3 = (const float*)d_in[7];
    const float* Wc = (const float*)d_in[8];
    const float* bc = (const float*)d_in[9];

    const int N = in_sizes[0] / 128;
    const int E = in_sizes[1] / 2;

    const int* row = ei;
    const int* col = ei + (size_t)E;

    const int NB  = (N + SPAN - 1) / SPAN;        // dest buckets (196)
    const int M   = NB * PART_B;                  // flattened hist size (~50K)
    const int PBE = (E + PART_B - 1) / PART_B;    // edges per partition block

    float* out   = (float*)d_out;                  // [N,4]
    float* y3out = (float*)d_out + (size_t)N * 4;  // [N,2]

    const int nblkN = (N + TPB - 1) / TPB;
    const int nblkE = (E + TPB - 1) / TPB;
    const int nblkW = (N * 64 + TPB - 1) / TPB;
    const int nblkG = (N * 16 + TPB - 1) / TPB;    // 16 threads/node
    const int nblkM = (M + 1 + TPB - 1) / TPB;
    const int nblkS = (M + SCAN_B - 1) / SCAN_B;   // scan blocks (~13)

    // Carve (~56.2MB). H is scanned in place (becomes O).
    size_t off = 0;
    auto carve = [&](size_t bytes) -> void* {
        void* r = (void*)((char*)d_ws + off);
        off += (bytes + 255) & ~(size_t)255;
        return r;
    };
    float*        dinv    = (float*)carve((size_t)N * 4);
    float*        dxw1    = (float*)carve((size_t)N * 4 * 4);
    float*        dxw2    = (float*)carve((size_t)N * 4 * 4);
    float*        dxw3    = (float*)carve((size_t)N * 2 * 4);
    unsigned int* indptr  = (unsigned int*)carve(((size_t)N + 1) * 4);
    uint32_t*     bsum    = (uint32_t*)carve(260 * 4);
    uint32_t*     H       = (uint32_t*)carve(((size_t)M + 1) * 4);  // -> O in place
    uint32_t*     bpack   = (uint32_t*)carve((size_t)E * 4);
    int*          csr_row = (int*)carve((size_t)E * 4);
    bool use_bucket = (off <= ws_size) && (NB <= 1024) && (N < (1 << 23));

    if (use_bucket) {
        size_t sort_lds = (size_t)SORT_CAP * 4;  // 140KB dynamic (+~6KB static)
        hipFuncSetAttribute((const void*)p_sort,
                            hipFuncAttributeMaxDynamicSharedMemorySize,
                            (int)sort_lds);
        p_hist<<<PART_B, PART_T, 0, stream>>>(col, H, NB, E, PBE);
        k_scan1<<<nblkS, SCAN_T, 0, stream>>>(H, H, bsum, M);         // in-place
        k_scan2<<<1, 32, 0, stream>>>(bsum, nblkS);
        k_scan3<<<nblkM, TPB, 0, stream>>>(H, bsum, H, M, E);         // in-place
        p_part<<<PART_B, PART_T, 0, stream>>>(row, col, H, bpack, NB, E, PBE);
        p_sort<<<NB, PART_T, sort_lds, stream>>>(bpack, H, x, W1, csr_row,
                                                 indptr, dinv, dxw1, NB, N, E);
        k_gather44<<<nblkG, TPB, 0, stream>>>(indptr, csr_row, dinv, dxw1, b1, W2, dxw2, N);
        k_gather42<<<nblkG, TPB, 0, stream>>>(indptr, csr_row, dinv, dxw2, b2, W3, dxw3, N);
        k_gather2out<<<nblkG, TPB, 0, stream>>>(indptr, csr_row, dinv, dxw3, b3, Wc, bc,
                                                out, y3out, N);
    } else {
        // R3 verified atomic-push fallback: recarve from base (~6MB).
        size_t foff = 0;
        auto fcarve = [&](size_t bytes) -> void* {
            void* r = (void*)((char*)d_ws + foff);
            foff += (bytes + 255) & ~(size_t)255;
            return r;
        };
        unsigned int* deg   = (unsigned int*)fcarve((size_t)N * 4);
        float*        fdinv = (float*)fcarve((size_t)N * 4);
        float*        xw    = (float*)fcarve((size_t)N * 4 * 4);
        float*        agg   = (float*)fcarve((size_t)N * 4 * 4);
        float*        xw3   = (float*)fcarve((size_t)N * 2 * 4);
        float*        agg3  = (float*)fcarve((size_t)N * 2 * 4);
        k_zero_deg<<<nblkN, TPB, 0, stream>>>(deg, N);
        k_deg<<<nblkE, TPB, 0, stream>>>(col, deg, E);
        k_dinv<<<nblkN, TPB, 0, stream>>>(deg, fdinv, N);
        k_xw1<<<nblkW, TPB, 0, stream>>>(x, W1, fdinv, xw, agg, N);
        k_prop4<<<nblkE, TPB, 0, stream>>>(row, col, fdinv, xw, agg, E);
        k_node2<<<nblkN, TPB, 0, stream>>>(b1, W2, fdinv, xw, agg, N);
        k_prop4<<<nblkE, TPB, 0, stream>>>(row, col, fdinv, xw, agg, E);
        k_node3<<<nblkN, TPB, 0, stream>>>(b2, W3, fdinv, agg, xw3, agg3, N);
        k_prop2<<<nblkE, TPB, 0, stream>>>(row, col, fdinv, xw3, agg3, E);
        k_out<<<nblkN, TPB, 0, stream>>>(b3, Wc, bc, agg3, out, y3out, N);
    }
}

// Round 16
// 196.429 us; speedup vs baseline: 1.4498x; 1.0972x over previous
//
#include <hip/hip_runtime.h>
#include <stdint.h>

#define TPB 256
#define SPAN 512        // nodes per dest bucket (bucket = col>>9)
#define LSH 9           // log2(SPAN)
#define PART_B 256      // partition blocks (one per CU)
#define PART_T 1024     // threads in hist/partition/sort kernels
#define SCAN_T 1024
#define SCAN_B 4096     // elements per scan block (1024 thr x 4)
#define SORT_CAP 35840  // words of dynamic LDS sort buffer (140KB); W ~32653±181

// ---------------------------------------------------------------------------
// GCN 3-layer forward on MI355X.
// R16 = R12 (verified best, 208.6us; R13/R14/R15 restructurings all
// regressed) + int4/uint4 vectorized edge passes. p_part was latency-bound
// (52us, VALU 2.6%, occ 33%, ~1TB/s): each thread had one serial
// {load->LDS-atomic->store} chain. 4 edges/thread/iter quadruples
// independent chains at unchanged occupancy/traffic. Applied to p_hist,
// p_part, p_sort (both window passes + int4 csr writeout). xw1d separate
// (full occupancy - R15 fusion regression confirmed the occupancy rule).
// Pipeline: p_hist | scan(in place) | p_part (512B runs, amp 1.1) |
// p_sort | xw1d | 3x CSR gather. agg[c] = dinv[c]*(sum dxw[r] + dxw[c]).
// WS ~56.2MB. R3 atomic-push fallback kept.
// ---------------------------------------------------------------------------

// ---------------- bucket partition ----------------

__global__ __launch_bounds__(PART_T) void p_hist(
    const int* __restrict__ col, uint32_t* __restrict__ H,
    int NB, int E, int PBE) {
    __shared__ uint32_t cnt[1024];
    for (int i = threadIdx.x; i < NB; i += PART_T) cnt[i] = 0u;
    __syncthreads();
    int blk = blockIdx.x;
    int s = blk * PBE, e = min(E, s + PBE);
    // s = blk*PBE; PBE multiple of 4 in practice; guard generally anyway.
    for (int i = s + (threadIdx.x << 2); i < e; i += (PART_T << 2)) {
        if (i + 4 <= e && ((i & 3) == 0)) {
            int4 c4 = *(const int4*)(col + i);
            atomicAdd(&cnt[c4.x >> LSH], 1u);
            atomicAdd(&cnt[c4.y >> LSH], 1u);
            atomicAdd(&cnt[c4.z >> LSH], 1u);
            atomicAdd(&cnt[c4.w >> LSH], 1u);
        } else {
            for (int k = i; k < min(e, i + 4); ++k)
                atomicAdd(&cnt[col[k] >> LSH], 1u);
        }
    }
    __syncthreads();
    for (int i = threadIdx.x; i < NB; i += PART_T)
        H[(size_t)i * PART_B + blk] = cnt[i];
}

__global__ __launch_bounds__(SCAN_T) void k_scan1(
    const unsigned int* __restrict__ in, unsigned int* __restrict__ partial,
    unsigned int* __restrict__ bsum, int M) {
    __shared__ unsigned int sm[SCAN_T];
    int tid  = threadIdx.x;
    int base = blockIdx.x * SCAN_B + tid * 4;
    unsigned int v0 = (base + 0 < M) ? in[base + 0] : 0u;
    unsigned int v1 = (base + 1 < M) ? in[base + 1] : 0u;
    unsigned int v2 = (base + 2 < M) ? in[base + 2] : 0u;
    unsigned int v3 = (base + 3 < M) ? in[base + 3] : 0u;
    unsigned int s = v0 + v1 + v2 + v3;
    sm[tid] = s;
    __syncthreads();
    for (int off = 1; off < SCAN_T; off <<= 1) {
        unsigned int t = (tid >= off) ? sm[tid - off] : 0u;
        __syncthreads();
        sm[tid] += t;
        __syncthreads();
    }
    unsigned int excl = sm[tid] - s;
    if (base + 0 < M) partial[base + 0] = excl;
    if (base + 1 < M) partial[base + 1] = excl + v0;
    if (base + 2 < M) partial[base + 2] = excl + v0 + v1;
    if (base + 3 < M) partial[base + 3] = excl + v0 + v1 + v2;
    if (tid == SCAN_T - 1) bsum[blockIdx.x] = sm[SCAN_T - 1];
}

__global__ void k_scan2(unsigned int* __restrict__ bsum, int nb) {
    if (threadIdx.x == 0 && blockIdx.x == 0) {
        unsigned int run = 0;
        for (int i = 0; i < nb; ++i) {
            unsigned int t = bsum[i];
            bsum[i] = run;
            run += t;
        }
    }
}

__global__ __launch_bounds__(TPB) void k_scan3(
    const unsigned int* __restrict__ partial, const unsigned int* __restrict__ bsum,
    unsigned int* __restrict__ outp, int M, int E) {
    int i = blockIdx.x * TPB + threadIdx.x;
    if (i < M) outp[i] = partial[i] + bsum[i / SCAN_B];
    if (i == 0) outp[M] = (unsigned int)E;
}

// Partition: bpack[slot] = (row<<LSH)|ldest, bucket-grouped, 512B runs.
// int4 edge loads: 4 independent atomic+store chains per thread per iter.
__global__ __launch_bounds__(PART_T) void p_part(
    const int* __restrict__ row, const int* __restrict__ col,
    const uint32_t* __restrict__ O, uint32_t* __restrict__ bpack,
    int NB, int E, int PBE) {
    __shared__ uint32_t cur[1024];
    int blk = blockIdx.x;
    for (int i = threadIdx.x; i < NB; i += PART_T)
        cur[i] = O[(size_t)i * PART_B + blk];
    __syncthreads();
    int s = blk * PBE, e = min(E, s + PBE);
    for (int i = s + (threadIdx.x << 2); i < e; i += (PART_T << 2)) {
        if (i + 4 <= e && ((i & 3) == 0)) {
            int4 c4 = *(const int4*)(col + i);
            int4 r4 = *(const int4*)(row + i);
            uint32_t s0 = atomicAdd(&cur[c4.x >> LSH], 1u);
            uint32_t s1 = atomicAdd(&cur[c4.y >> LSH], 1u);
            uint32_t s2 = atomicAdd(&cur[c4.z >> LSH], 1u);
            uint32_t s3 = atomicAdd(&cur[c4.w >> LSH], 1u);
            bpack[s0] = ((uint32_t)r4.x << LSH) | (uint32_t)(c4.x & (SPAN - 1));
            bpack[s1] = ((uint32_t)r4.y << LSH) | (uint32_t)(c4.y & (SPAN - 1));
            bpack[s2] = ((uint32_t)r4.z << LSH) | (uint32_t)(c4.z & (SPAN - 1));
            bpack[s3] = ((uint32_t)r4.w << LSH) | (uint32_t)(c4.w & (SPAN - 1));
        } else {
            for (int k = i; k < min(e, i + 4); ++k) {
                int c = col[k];
                uint32_t slot = atomicAdd(&cur[c >> LSH], 1u);
                bpack[slot] = ((uint32_t)row[k] << LSH) | (uint32_t)(c & (SPAN - 1));
            }
        }
    }
}

// Per-bucket counting sort (512-node buckets): uint4 window reads, LDS
// staging (140KB dynamic), int4 coalesced csr writeout. Emits indptr+dinv.
extern __shared__ uint32_t sort_buf[];
__global__ __launch_bounds__(PART_T) void p_sort(
    const uint32_t* __restrict__ bpack, const uint32_t* __restrict__ O,
    int* __restrict__ csr_row, unsigned int* __restrict__ indptr,
    float* __restrict__ dinv, int NB, int N, int E) {
    __shared__ uint32_t hist[SPAN];
    __shared__ uint32_t cur[SPAN];
    int b = blockIdx.x;
    int t = threadIdx.x;
    if (t < SPAN) hist[t] = 0u;
    __syncthreads();
    uint32_t s = O[(size_t)b * PART_B];
    uint32_t e = O[(size_t)(b + 1) * PART_B];  // b+1==NB -> O[M]==E sentinel
    uint32_t W = e - s;
    uint32_t as = (s + 3u) & ~3u;  // first 16B-aligned index
    // hist pass: scalar prologue + uint4 main + guarded tail
    if ((uint32_t)t < as - s && s + t < e)
        atomicAdd(&hist[bpack[s + t] & (SPAN - 1)], 1u);
    for (uint32_t i = as + ((uint32_t)t << 2); i < e; i += (PART_T << 2)) {
        if (i + 4u <= e) {
            uint4 v4 = *(const uint4*)(bpack + i);
            atomicAdd(&hist[v4.x & (SPAN - 1)], 1u);
            atomicAdd(&hist[v4.y & (SPAN - 1)], 1u);
            atomicAdd(&hist[v4.z & (SPAN - 1)], 1u);
            atomicAdd(&hist[v4.w & (SPAN - 1)], 1u);
        } else {
            for (uint32_t k = i; k < e; ++k)
                atomicAdd(&hist[bpack[k] & (SPAN - 1)], 1u);
        }
    }
    __syncthreads();
    if (t < SPAN) cur[t] = hist[t];
    __syncthreads();
    for (int off = 1; off < SPAN; off <<= 1) {  // Hillis-Steele inclusive scan
        uint32_t v = (t < SPAN && t >= off) ? cur[t - off] : 0u;
        __syncthreads();
        if (t < SPAN) cur[t] += v;
        __syncthreads();
    }
    if (t < SPAN) {
        uint32_t excl = cur[t] - hist[t];
        int n = b * SPAN + t;
        if (n < N) {
            indptr[n] = s + excl;                      // dense: csr base == bpack base
            dinv[n]   = rsqrtf((float)(hist[t] + 1u)); // +1 = self loop
            if (n == N - 1) indptr[N] = (unsigned int)E;
        }
        cur[t] = excl;  // window-local cursor
    }
    __syncthreads();
    if (W <= SORT_CAP) {
        // scatter into LDS (uint4 reads)
        if ((uint32_t)t < as - s && s + t < e) {
            uint32_t v = bpack[s + t];
            uint32_t slot = atomicAdd(&cur[v & (SPAN - 1)], 1u);
            sort_buf[slot] = v >> LSH;
        }
        for (uint32_t i = as + ((uint32_t)t << 2); i < e; i += (PART_T << 2)) {
            if (i + 4u <= e) {
                uint4 v4 = *(const uint4*)(bpack + i);
                uint32_t s0 = atomicAdd(&cur[v4.x & (SPAN - 1)], 1u);
                uint32_t s1 = atomicAdd(&cur[v4.y & (SPAN - 1)], 1u);
                uint32_t s2 = atomicAdd(&cur[v4.z & (SPAN - 1)], 1u);
                uint32_t s3 = atomicAdd(&cur[v4.w & (SPAN - 1)], 1u);
                sort_buf[s0] = v4.x >> LSH;
                sort_buf[s1] = v4.y >> LSH;
                sort_buf[s2] = v4.z >> LSH;
                sort_buf[s3] = v4.w >> LSH;
            } else {
                for (uint32_t k = i; k < e; ++k) {
                    uint32_t v = bpack[k];
                    uint32_t slot = atomicAdd(&cur[v & (SPAN - 1)], 1u);
                    sort_buf[slot] = v >> LSH;
                }
            }
        }
        __syncthreads();
        // coalesced writeout: scalar prologue to alignment, then int4
        uint32_t pro = as - s;  // elements before aligned base (0..3)
        if ((uint32_t)t < pro && (uint32_t)t < W) csr_row[s + t] = (int)sort_buf[t];
        for (uint32_t j = pro + ((uint32_t)t << 2); j < W; j += (PART_T << 2)) {
            if (j + 4u <= W) {
                *(int4*)(csr_row + s + j) =
                    make_int4((int)sort_buf[j], (int)sort_buf[j + 1],
                              (int)sort_buf[j + 2], (int)sort_buf[j + 3]);
            } else {
                for (uint32_t k = j; k < W; ++k) csr_row[s + k] = (int)sort_buf[k];
            }
        }
    } else {
        // statistical fallback (+17sigma): direct scattered stores
        for (uint32_t i = s + t; i < e; i += PART_T) {
            uint32_t v = bpack[i];
            uint32_t slot = atomicAdd(&cur[v & (SPAN - 1)], 1u);
            csr_row[s + slot] = (int)(v >> LSH);
        }
    }
}

// ---------------- node / gather kernels (unchanged from R12) ----------------

__global__ __launch_bounds__(TPB) void k_xw1d(
    const float* __restrict__ x, const float* __restrict__ W1,
    const float* __restrict__ dinv, float* __restrict__ dxw1, int N) {
    __shared__ float sW[512];  // 128 x 4
    for (int t = threadIdx.x; t < 512; t += TPB) sW[t] = W1[t];
    __syncthreads();
    int gid  = blockIdx.x * TPB + threadIdx.x;
    int node = gid >> 6;
    int lane = threadIdx.x & 63;
    if (node >= N) return;
    float2 v = *(const float2*)(x + (size_t)node * 128 + 2 * lane);
    const float* w0 = &sW[(2 * lane) * 4];
    const float* w1 = &sW[(2 * lane + 1) * 4];
    float a[4];
#pragma unroll
    for (int j = 0; j < 4; ++j) a[j] = v.x * w0[j] + v.y * w1[j];
#pragma unroll
    for (int off = 32; off > 0; off >>= 1) {
#pragma unroll
        for (int j = 0; j < 4; ++j) a[j] += __shfl_down(a[j], off);
    }
    if (lane == 0) {
        float d = dinv[node];
        *(float4*)(dxw1 + (size_t)node * 4) =
            make_float4(d * a[0], d * a[1], d * a[2], d * a[3]);
    }
}

__global__ __launch_bounds__(TPB) void k_gather44(
    const unsigned int* __restrict__ indptr, const int* __restrict__ csr_row,
    const float* __restrict__ dinv, const float* __restrict__ dxw_in,
    const float* __restrict__ b, const float* __restrict__ W,
    float* __restrict__ dxw_out, int N) {
    int gid  = blockIdx.x * TPB + threadIdx.x;
    int node = gid >> 4;
    int sub  = gid & 15;
    if (node >= N) return;
    int e0 = (int)indptr[node], e1 = (int)indptr[node + 1];
    float4 acc = make_float4(0.f, 0.f, 0.f, 0.f);
    for (int j = e0 + sub; j < e1; j += 16) {
        int r = csr_row[j];
        float4 m = *(const float4*)(dxw_in + (size_t)r * 4);
        acc.x += m.x; acc.y += m.y; acc.z += m.z; acc.w += m.w;
    }
#pragma unroll
    for (int off = 1; off < 16; off <<= 1) {
        acc.x += __shfl_xor(acc.x, off);
        acc.y += __shfl_xor(acc.y, off);
        acc.z += __shfl_xor(acc.z, off);
        acc.w += __shfl_xor(acc.w, off);
    }
    if (sub == 0) {
        float d = dinv[node];
        float4 sv = *(const float4*)(dxw_in + (size_t)node * 4);
        float h0 = fmaxf(d * (acc.x + sv.x) + b[0], 0.f);
        float h1 = fmaxf(d * (acc.y + sv.y) + b[1], 0.f);
        float h2 = fmaxf(d * (acc.z + sv.z) + b[2], 0.f);
        float h3 = fmaxf(d * (acc.w + sv.w) + b[3], 0.f);
        float o[4];
#pragma unroll
        for (int j = 0; j < 4; ++j)
            o[j] = h0 * W[0 * 4 + j] + h1 * W[1 * 4 + j] +
                   h2 * W[2 * 4 + j] + h3 * W[3 * 4 + j];
        *(float4*)(dxw_out + (size_t)node * 4) =
            make_float4(d * o[0], d * o[1], d * o[2], d * o[3]);
    }
}

__global__ __launch_bounds__(TPB) void k_gather42(
    const unsigned int* __restrict__ indptr, const int* __restrict__ csr_row,
    const float* __restrict__ dinv, const float* __restrict__ dxw_in,
    const float* __restrict__ b, const float* __restrict__ W,
    float* __restrict__ dxw_out, int N) {
    int gid  = blockIdx.x * TPB + threadIdx.x;
    int node = gid >> 4;
    int sub  = gid & 15;
    if (node >= N) return;
    int e0 = (int)indptr[node], e1 = (int)indptr[node + 1];
    float4 acc = make_float4(0.f, 0.f, 0.f, 0.f);
    for (int j = e0 + sub; j < e1; j += 16) {
        int r = csr_row[j];
        float4 m = *(const float4*)(dxw_in + (size_t)r * 4);
        acc.x += m.x; acc.y += m.y; acc.z += m.z; acc.w += m.w;
    }
#pragma unroll
    for (int off = 1; off < 16; off <<= 1) {
        acc.x += __shfl_xor(acc.x, off);
        acc.y += __shfl_xor(acc.y, off);
        acc.z += __shfl_xor(acc.z, off);
        acc.w += __shfl_xor(acc.w, off);
    }
    if (sub == 0) {
        float d = dinv[node];
        float4 sv = *(const float4*)(dxw_in + (size_t)node * 4);
        float h0 = fmaxf(d * (acc.x + sv.x) + b[0], 0.f);
        float h1 = fmaxf(d * (acc.y + sv.y) + b[1], 0.f);
        float h2 = fmaxf(d * (acc.z + sv.z) + b[2], 0.f);
        float h3 = fmaxf(d * (acc.w + sv.w) + b[3], 0.f);
        float o0 = h0 * W[0] + h1 * W[2] + h2 * W[4] + h3 * W[6];
        float o1 = h0 * W[1] + h1 * W[3] + h2 * W[5] + h3 * W[7];
        *(float2*)(dxw_out + (size_t)node * 2) = make_float2(d * o0, d * o1);
    }
}

__global__ __launch_bounds__(TPB) void k_gather2out(
    const unsigned int* __restrict__ indptr, const int* __restrict__ csr_row,
    const float* __restrict__ dinv, const float* __restrict__ dxw3,
    const float* __restrict__ b3, const float* __restrict__ Wc,
    const float* __restrict__ bc,
    float* __restrict__ out, float* __restrict__ y3out, int N) {
    int gid  = blockIdx.x * TPB + threadIdx.x;
    int node = gid >> 4;
    int sub  = gid & 15;
    if (node >= N) return;
    int e0 = (int)indptr[node], e1 = (int)indptr[node + 1];
    float ax = 0.f, ay = 0.f;
    for (int j = e0 + sub; j < e1; j += 16) {
        int r = csr_row[j];
        float2 m = *(const float2*)(dxw3 + (size_t)r * 2);
        ax += m.x; ay += m.y;
    }
#pragma unroll
    for (int off = 1; off < 16; off <<= 1) {
        ax += __shfl_xor(ax, off);
        ay += __shfl_xor(ay, off);
    }
    if (sub == 0) {
        float d = dinv[node];
        float2 sv = *(const float2*)(dxw3 + (size_t)node * 2);
        float y0 = fmaxf(d * (ax + sv.x) + b3[0], 0.f);
        float y1 = fmaxf(d * (ay + sv.y) + b3[1], 0.f);
        float o[4];
#pragma unroll
        for (int j = 0; j < 4; ++j)
            o[j] = y0 * Wc[0 * 4 + j] + y1 * Wc[1 * 4 + j] + bc[j];
        *(float4*)(out + (size_t)node * 4) = make_float4(o[0], o[1], o[2], o[3]);
        *(float2*)(y3out + (size_t)node * 2) = make_float2(y0, y1);
    }
}

// ---------------- R3 fallback kernels (atomic push path) ----------------

__global__ __launch_bounds__(TPB) void k_zero_deg(unsigned int* __restrict__ deg, int N) {
    int i = blockIdx.x * TPB + threadIdx.x;
    if (i < N) deg[i] = 0u;
}

__global__ __launch_bounds__(TPB) void k_deg(
    const int* __restrict__ col, unsigned int* __restrict__ deg, int E) {
    int e = blockIdx.x * TPB + threadIdx.x;
    if (e >= E) return;
    atomicAdd(&deg[col[e]], 1u);
}

__global__ __launch_bounds__(TPB) void k_dinv(const unsigned int* __restrict__ deg,
                                              float* __restrict__ dinv, int N) {
    int i = blockIdx.x * TPB + threadIdx.x;
    if (i < N) dinv[i] = rsqrtf((float)(deg[i] + 1u));
}

__global__ __launch_bounds__(TPB) void k_xw1(
    const float* __restrict__ x, const float* __restrict__ W1,
    const float* __restrict__ dinv,
    float* __restrict__ xw, float* __restrict__ agg, int N) {
    __shared__ float sW[512];
    for (int t = threadIdx.x; t < 512; t += TPB) sW[t] = W1[t];
    __syncthreads();
    int gid  = blockIdx.x * TPB + threadIdx.x;
    int node = gid >> 6;
    int lane = threadIdx.x & 63;
    if (node >= N) return;
    float2 v = *(const float2*)(x + (size_t)node * 128 + 2 * lane);
    const float* w0 = &sW[(2 * lane) * 4];
    const float* w1 = &sW[(2 * lane + 1) * 4];
    float a[4];
#pragma unroll
    for (int j = 0; j < 4; ++j) a[j] = v.x * w0[j] + v.y * w1[j];
#pragma unroll
    for (int off = 32; off > 0; off >>= 1) {
#pragma unroll
        for (int j = 0; j < 4; ++j) a[j] += __shfl_down(a[j], off);
    }
    if (lane == 0) {
        float d  = dinv[node];
        float d2 = d * d;
        *(float4*)(xw  + (size_t)node * 4) = make_float4(a[0], a[1], a[2], a[3]);
        *(float4*)(agg + (size_t)node * 4) =
            make_float4(d2 * a[0], d2 * a[1], d2 * a[2], d2 * a[3]);
    }
}

__global__ __launch_bounds__(TPB) void k_prop4(
    const int* __restrict__ row, const int* __restrict__ col,
    const float* __restrict__ dinv,
    const float* __restrict__ xw, float* __restrict__ agg, int E) {
    int e = blockIdx.x * TPB + threadIdx.x;
    if (e >= E) return;
    int r = row[e];
    int c = col[e];
    float nv = dinv[r] * dinv[c];
    float4 m = *(const float4*)(xw + (size_t)r * 4);
    float* a = agg + (size_t)c * 4;
    atomicAdd(a + 0, nv * m.x);
    atomicAdd(a + 1, nv * m.y);
    atomicAdd(a + 2, nv * m.z);
    atomicAdd(a + 3, nv * m.w);
}

__global__ __launch_bounds__(TPB) void k_prop2(
    const int* __restrict__ row, const int* __restrict__ col,
    const float* __restrict__ dinv,
    const float* __restrict__ xw2, float* __restrict__ agg2, int E) {
    int e = blockIdx.x * TPB + threadIdx.x;
    if (e >= E) return;
    int r = row[e];
    int c = col[e];
    float nv = dinv[r] * dinv[c];
    float2 m = *(const float2*)(xw2 + (size_t)r * 2);
    float* a = agg2 + (size_t)c * 2;
    atomicAdd(a + 0, nv * m.x);
    atomicAdd(a + 1, nv * m.y);
}

__global__ __launch_bounds__(TPB) void k_node2(
    const float* __restrict__ b1, const float* __restrict__ W2,
    const float* __restrict__ dinv,
    float* __restrict__ xw, float* __restrict__ agg, int N) {
    int i = blockIdx.x * TPB + threadIdx.x;
    if (i >= N) return;
    float4 av = *(const float4*)(agg + (size_t)i * 4);
    float h0 = fmaxf(av.x + b1[0], 0.f);
    float h1 = fmaxf(av.y + b1[1], 0.f);
    float h2 = fmaxf(av.z + b1[2], 0.f);
    float h3 = fmaxf(av.w + b1[3], 0.f);
    float o[4];
#pragma unroll
    for (int j = 0; j < 4; ++j)
        o[j] = h0 * W2[0 * 4 + j] + h1 * W2[1 * 4 + j] +
               h2 * W2[2 * 4 + j] + h3 * W2[3 * 4 + j];
    float d  = dinv[i];
    float d2 = d * d;
    *(float4*)(xw  + (size_t)i * 4) = make_float4(o[0], o[1], o[2], o[3]);
    *(float4*)(agg + (size_t)i * 4) = make_float4(d2 * o[0], d2 * o[1], d2 * o[2], d2 * o[3]);
}

__global__ __launch_bounds__(TPB) void k_node3(
    const float* __restrict__ b2, const float* __restrict__ W3,
    const float* __restrict__ dinv,
    const float* __restrict__ agg,
    float* __restrict__ xw3, float* __restrict__ agg3, int N) {
    int i = blockIdx.x * TPB + threadIdx.x;
    if (i >= N) return;
    float4 av = *(const float4*)(agg + (size_t)i * 4);
    float h0 = fmaxf(av.x + b2[0], 0.f);
    float h1 = fmaxf(av.y + b2[1], 0.f);
    float h2 = fmaxf(av.z + b2[2], 0.f);
    float h3 = fmaxf(av.w + b2[3], 0.f);
    float o0 = h0 * W3[0] + h1 * W3[2] + h2 * W3[4] + h3 * W3[6];
    float o1 = h0 * W3[1] + h1 * W3[3] + h2 * W3[5] + h3 * W3[7];
    float d  = dinv[i];
    float d2 = d * d;
    *(float2*)(xw3  + (size_t)i * 2) = make_float2(o0, o1);
    *(float2*)(agg3 + (size_t)i * 2) = make_float2(d2 * o0, d2 * o1);
}

__global__ __launch_bounds__(TPB) void k_out(
    const float* __restrict__ b3, const float* __restrict__ Wc,
    const float* __restrict__ bc,
    const float* __restrict__ agg3,
    float* __restrict__ out, float* __restrict__ y3out, int N) {
    int i = blockIdx.x * TPB + threadIdx.x;
    if (i >= N) return;
    float2 av = *(const float2*)(agg3 + (size_t)i * 2);
    float y0 = fmaxf(av.x + b3[0], 0.f);
    float y1 = fmaxf(av.y + b3[1], 0.f);
    float o[4];
#pragma unroll
    for (int j = 0; j < 4; ++j)
        o[j] = y0 * Wc[0 * 4 + j] + y1 * Wc[1 * 4 + j] + bc[j];
    *(float4*)(out + (size_t)i * 4) = make_float4(o[0], o[1], o[2], o[3]);
    *(float2*)(y3out + (size_t)i * 2) = make_float2(y0, y1);
}

extern "C" void kernel_launch(void* const* d_in, const int* in_sizes, int n_in,
                              void* d_out, int out_size, void* d_ws, size_t ws_size,
                              hipStream_t stream) {
    const float* x  = (const float*)d_in[0];
    const int*   ei = (const int*)d_in[1];   // int32 (harness converts integer inputs)
    const float* W1 = (const float*)d_in[2];
    const float* b1 = (const float*)d_in[3];
    const float* W2 = (const float*)d_in[4];
    const float* b2 = (const float*)d_in[5];
    const float* W3 = (const float*)d_in[6];
    const float* b3 = (const float*)d_in[7];
    const float* Wc = (const float*)d_in[8];
    const float* bc = (const float*)d_in[9];

    const int N = in_sizes[0] / 128;
    const int E = in_sizes[1] / 2;

    const int* row = ei;
    const int* col = ei + (size_t)E;

    const int NB  = (N + SPAN - 1) / SPAN;        // dest buckets (196)
    const int M   = NB * PART_B;                  // flattened hist size (~50K)
    const int PBE = (E + PART_B - 1) / PART_B;    // edges per partition block

    float* out   = (float*)d_out;                  // [N,4]
    float* y3out = (float*)d_out + (size_t)N * 4;  // [N,2]

    const int nblkN = (N + TPB - 1) / TPB;
    const int nblkE = (E + TPB - 1) / TPB;
    const int nblkW = (N * 64 + TPB - 1) / TPB;
    const int nblkG = (N * 16 + TPB - 1) / TPB;    // 16 threads/node
    const int nblkM = (M + 1 + TPB - 1) / TPB;
    const int nblkS = (M + SCAN_B - 1) / SCAN_B;   // scan blocks (~13)

    // Carve (~56.2MB). H is scanned in place (becomes O).
    size_t off = 0;
    auto carve = [&](size_t bytes) -> void* {
        void* r = (void*)((char*)d_ws + off);
        off += (bytes + 255) & ~(size_t)255;
        return r;
    };
    float*        dinv    = (float*)carve((size_t)N * 4);
    float*        dxw1    = (float*)carve((size_t)N * 4 * 4);
    float*        dxw2    = (float*)carve((size_t)N * 4 * 4);
    float*        dxw3    = (float*)carve((size_t)N * 2 * 4);
    unsigned int* indptr  = (unsigned int*)carve(((size_t)N + 1) * 4);
    uint32_t*     bsum    = (uint32_t*)carve(260 * 4);
    uint32_t*     H       = (uint32_t*)carve(((size_t)M + 1) * 4);  // -> O in place
    uint32_t*     bpack   = (uint32_t*)carve((size_t)E * 4);
    int*          csr_row = (int*)carve((size_t)E * 4);
    bool use_bucket = (off <= ws_size) && (NB <= 1024) && (N < (1 << 23));

    if (use_bucket) {
        size_t sort_lds = (size_t)SORT_CAP * 4;  // 140KB dynamic (+4KB static)
        hipFuncSetAttribute((const void*)p_sort,
                            hipFuncAttributeMaxDynamicSharedMemorySize,
                            (int)sort_lds);
        p_hist<<<PART_B, PART_T, 0, stream>>>(col, H, NB, E, PBE);
        k_scan1<<<nblkS, SCAN_T, 0, stream>>>(H, H, bsum, M);         // in-place
        k_scan2<<<1, 32, 0, stream>>>(bsum, nblkS);
        k_scan3<<<nblkM, TPB, 0, stream>>>(H, bsum, H, M, E);         // in-place
        p_part<<<PART_B, PART_T, 0, stream>>>(row, col, H, bpack, NB, E, PBE);
        p_sort<<<NB, PART_T, sort_lds, stream>>>(bpack, H, csr_row, indptr,
                                                 dinv, NB, N, E);
        k_xw1d<<<nblkW, TPB, 0, stream>>>(x, W1, dinv, dxw1, N);
        k_gather44<<<nblkG, TPB, 0, stream>>>(indptr, csr_row, dinv, dxw1, b1, W2, dxw2, N);
        k_gather42<<<nblkG, TPB, 0, stream>>>(indptr, csr_row, dinv, dxw2, b2, W3, dxw3, N);
        k_gather2out<<<nblkG, TPB, 0, stream>>>(indptr, csr_row, dinv, dxw3, b3, Wc, bc,
                                                out, y3out, N);
    } else {
        // R3 verified atomic-push fallback: recarve from base (~6MB).
        size_t foff = 0;
        auto fcarve = [&](size_t bytes) -> void* {
            void* r = (void*)((char*)d_ws + foff);
            foff += (bytes + 255) & ~(size_t)255;
            return r;
        };
        unsigned int* deg   = (unsigned int*)fcarve((size_t)N * 4);
        float*        fdinv = (float*)fcarve((size_t)N * 4);
        float*        xw    = (float*)fcarve((size_t)N * 4 * 4);
        float*        agg   = (float*)fcarve((size_t)N * 4 * 4);
        float*        xw3   = (float*)fcarve((size_t)N * 2 * 4);
        float*        agg3  = (float*)fcarve((size_t)N * 2 * 4);
        k_zero_deg<<<nblkN, TPB, 0, stream>>>(deg, N);
        k_deg<<<nblkE, TPB, 0, stream>>>(col, deg, E);
        k_dinv<<<nblkN, TPB, 0, stream>>>(deg, fdinv, N);
        k_xw1<<<nblkW, TPB, 0, stream>>>(x, W1, fdinv, xw, agg, N);
        k_prop4<<<nblkE, TPB, 0, stream>>>(row, col, fdinv, xw, agg, E);
        k_node2<<<nblkN, TPB, 0, stream>>>(b1, W2, fdinv, xw, agg, N);
        k_prop4<<<nblkE, TPB, 0, stream>>>(row, col, fdinv, xw, agg, E);
        k_node3<<<nblkN, TPB, 0, stream>>>(b2, W3, fdinv, agg, xw3, agg3, N);
        k_prop2<<<nblkE, TPB, 0, stream>>>(row, col, fdinv, xw3, agg3, E);
        k_out<<<nblkN, TPB, 0, stream>>>(b3, Wc, bc, agg3, out, y3out, N);
    }
}

// Round 17
// 184.638 us; speedup vs baseline: 1.5424x; 1.0639x over previous
//
#include <hip/hip_runtime.h>
#include <stdint.h>

#define TPB 256
#define SPAN 512        // nodes per dest bucket (bucket = col>>9)
#define LSH 9           // log2(SPAN)
#define PART_B 256      // partition blocks (one per CU)
#define PART_T 1024     // threads in hist/partition/sort kernels
#define SCAN_T 1024
#define SCAN_B 4096     // elements per scan block (1024 thr x 4)
#define SORT_CAP 35840  // words of dynamic LDS sort buffer (140KB); W ~32653±181

// ---------------------------------------------------------------------------
// GCN 3-layer forward on MI355X.
// R17 = R16 (196.4us) with p_part ILP done right. R16's int4 p_part raised
// write amp 1.1->1.6 (consecutive-4-edges-per-lane broke per-instruction
// slot clustering); gain ~= loss. Now STRIDED unroll: thread processes
// edges {i, i+PART_T, i+2PT, i+3PT} -> every load/store instruction still
// covers 64 consecutive edges per wave (R12's amp-1.1 pattern) with 4
// independent chains per thread. Also xw1d -> float4 2-nodes-per-wave
// (half-wave shuffle reduce), halving instructions on its 51MB read.
// p_hist/p_sort keep R16 vectorization (contiguous reads, no amp issue).
// Pipeline: p_hist | scan(in place) | p_part | p_sort | xw1d | 3x gather.
// agg[c] = dinv[c]*(sum dxw[r] + dxw[c]). WS ~56.2MB. R3 fallback kept.
// ---------------------------------------------------------------------------

// ---------------- bucket partition ----------------

__global__ __launch_bounds__(PART_T) void p_hist(
    const int* __restrict__ col, uint32_t* __restrict__ H,
    int NB, int E, int PBE) {
    __shared__ uint32_t cnt[1024];
    for (int i = threadIdx.x; i < NB; i += PART_T) cnt[i] = 0u;
    __syncthreads();
    int blk = blockIdx.x;
    int s = blk * PBE, e = min(E, s + PBE);
    for (int i = s + (threadIdx.x << 2); i < e; i += (PART_T << 2)) {
        if (i + 4 <= e && ((i & 3) == 0)) {
            int4 c4 = *(const int4*)(col + i);
            atomicAdd(&cnt[c4.x >> LSH], 1u);
            atomicAdd(&cnt[c4.y >> LSH], 1u);
            atomicAdd(&cnt[c4.z >> LSH], 1u);
            atomicAdd(&cnt[c4.w >> LSH], 1u);
        } else {
            for (int k = i; k < min(e, i + 4); ++k)
                atomicAdd(&cnt[col[k] >> LSH], 1u);
        }
    }
    __syncthreads();
    for (int i = threadIdx.x; i < NB; i += PART_T)
        H[(size_t)i * PART_B + blk] = cnt[i];
}

__global__ __launch_bounds__(SCAN_T) void k_scan1(
    const unsigned int* __restrict__ in, unsigned int* __restrict__ partial,
    unsigned int* __restrict__ bsum, int M) {
    __shared__ unsigned int sm[SCAN_T];
    int tid  = threadIdx.x;
    int base = blockIdx.x * SCAN_B + tid * 4;
    unsigned int v0 = (base + 0 < M) ? in[base + 0] : 0u;
    unsigned int v1 = (base + 1 < M) ? in[base + 1] : 0u;
    unsigned int v2 = (base + 2 < M) ? in[base + 2] : 0u;
    unsigned int v3 = (base + 3 < M) ? in[base + 3] : 0u;
    unsigned int s = v0 + v1 + v2 + v3;
    sm[tid] = s;
    __syncthreads();
    for (int off = 1; off < SCAN_T; off <<= 1) {
        unsigned int t = (tid >= off) ? sm[tid - off] : 0u;
        __syncthreads();
        sm[tid] += t;
        __syncthreads();
    }
    unsigned int excl = sm[tid] - s;
    if (base + 0 < M) partial[base + 0] = excl;
    if (base + 1 < M) partial[base + 1] = excl + v0;
    if (base + 2 < M) partial[base + 2] = excl + v0 + v1;
    if (base + 3 < M) partial[base + 3] = excl + v0 + v1 + v2;
    if (tid == SCAN_T - 1) bsum[blockIdx.x] = sm[SCAN_T - 1];
}

__global__ void k_scan2(unsigned int* __restrict__ bsum, int nb) {
    if (threadIdx.x == 0 && blockIdx.x == 0) {
        unsigned int run = 0;
        for (int i = 0; i < nb; ++i) {
            unsigned int t = bsum[i];
            bsum[i] = run;
            run += t;
        }
    }
}

__global__ __launch_bounds__(TPB) void k_scan3(
    const unsigned int* __restrict__ partial, const unsigned int* __restrict__ bsum,
    unsigned int* __restrict__ outp, int M, int E) {
    int i = blockIdx.x * TPB + threadIdx.x;
    if (i < M) outp[i] = partial[i] + bsum[i / SCAN_B];
    if (i == 0) outp[M] = (unsigned int)E;
}

// Partition: bpack[slot] = (row<<LSH)|ldest, bucket-grouped, 512B runs.
// STRIDED 4x unroll: per-instruction wave pattern = 64 consecutive edges
// (amp-1.1 preserved), 4 independent load/atomic/store chains per thread.
__global__ __launch_bounds__(PART_T) void p_part(
    const int* __restrict__ row, const int* __restrict__ col,
    const uint32_t* __restrict__ O, uint32_t* __restrict__ bpack,
    int NB, int E, int PBE) {
    __shared__ uint32_t cur[1024];
    int blk = blockIdx.x;
    for (int i = threadIdx.x; i < NB; i += PART_T)
        cur[i] = O[(size_t)i * PART_B + blk];
    __syncthreads();
    int s = blk * PBE, e = min(E, s + PBE);
    int i = s + threadIdx.x;
    for (; i + 3 * PART_T < e; i += 4 * PART_T) {
        int c0 = col[i];
        int c1 = col[i + PART_T];
        int c2 = col[i + 2 * PART_T];
        int c3 = col[i + 3 * PART_T];
        int r0 = row[i];
        int r1 = row[i + PART_T];
        int r2 = row[i + 2 * PART_T];
        int r3 = row[i + 3 * PART_T];
        uint32_t s0 = atomicAdd(&cur[c0 >> LSH], 1u);
        uint32_t s1 = atomicAdd(&cur[c1 >> LSH], 1u);
        uint32_t s2 = atomicAdd(&cur[c2 >> LSH], 1u);
        uint32_t s3 = atomicAdd(&cur[c3 >> LSH], 1u);
        bpack[s0] = ((uint32_t)r0 << LSH) | (uint32_t)(c0 & (SPAN - 1));
        bpack[s1] = ((uint32_t)r1 << LSH) | (uint32_t)(c1 & (SPAN - 1));
        bpack[s2] = ((uint32_t)r2 << LSH) | (uint32_t)(c2 & (SPAN - 1));
        bpack[s3] = ((uint32_t)r3 << LSH) | (uint32_t)(c3 & (SPAN - 1));
    }
    for (; i < e; i += PART_T) {
        int c = col[i];
        uint32_t slot = atomicAdd(&cur[c >> LSH], 1u);
        bpack[slot] = ((uint32_t)row[i] << LSH) | (uint32_t)(c & (SPAN - 1));
    }
}

// Per-bucket counting sort (512-node buckets): uint4 window reads, LDS
// staging (140KB dynamic), int4 coalesced csr writeout. Emits indptr+dinv.
extern __shared__ uint32_t sort_buf[];
__global__ __launch_bounds__(PART_T) void p_sort(
    const uint32_t* __restrict__ bpack, const uint32_t* __restrict__ O,
    int* __restrict__ csr_row, unsigned int* __restrict__ indptr,
    float* __restrict__ dinv, int NB, int N, int E) {
    __shared__ uint32_t hist[SPAN];
    __shared__ uint32_t cur[SPAN];
    int b = blockIdx.x;
    int t = threadIdx.x;
    if (t < SPAN) hist[t] = 0u;
    __syncthreads();
    uint32_t s = O[(size_t)b * PART_B];
    uint32_t e = O[(size_t)(b + 1) * PART_B];  // b+1==NB -> O[M]==E sentinel
    uint32_t W = e - s;
    uint32_t as = (s + 3u) & ~3u;  // first 16B-aligned index
    if ((uint32_t)t < as - s && s + t < e)
        atomicAdd(&hist[bpack[s + t] & (SPAN - 1)], 1u);
    for (uint32_t i = as + ((uint32_t)t << 2); i < e; i += (PART_T << 2)) {
        if (i + 4u <= e) {
            uint4 v4 = *(const uint4*)(bpack + i);
            atomicAdd(&hist[v4.x & (SPAN - 1)], 1u);
            atomicAdd(&hist[v4.y & (SPAN - 1)], 1u);
            atomicAdd(&hist[v4.z & (SPAN - 1)], 1u);
            atomicAdd(&hist[v4.w & (SPAN - 1)], 1u);
        } else {
            for (uint32_t k = i; k < e; ++k)
                atomicAdd(&hist[bpack[k] & (SPAN - 1)], 1u);
        }
    }
    __syncthreads();
    if (t < SPAN) cur[t] = hist[t];
    __syncthreads();
    for (int off = 1; off < SPAN; off <<= 1) {  // Hillis-Steele inclusive scan
        uint32_t v = (t < SPAN && t >= off) ? cur[t - off] : 0u;
        __syncthreads();
        if (t < SPAN) cur[t] += v;
        __syncthreads();
    }
    if (t < SPAN) {
        uint32_t excl = cur[t] - hist[t];
        int n = b * SPAN + t;
        if (n < N) {
            indptr[n] = s + excl;                      // dense: csr base == bpack base
            dinv[n]   = rsqrtf((float)(hist[t] + 1u)); // +1 = self loop
            if (n == N - 1) indptr[N] = (unsigned int)E;
        }
        cur[t] = excl;  // window-local cursor
    }
    __syncthreads();
    if (W <= SORT_CAP) {
        if ((uint32_t)t < as - s && s + t < e) {
            uint32_t v = bpack[s + t];
            uint32_t slot = atomicAdd(&cur[v & (SPAN - 1)], 1u);
            sort_buf[slot] = v >> LSH;
        }
        for (uint32_t i = as + ((uint32_t)t << 2); i < e; i += (PART_T << 2)) {
            if (i + 4u <= e) {
                uint4 v4 = *(const uint4*)(bpack + i);
                uint32_t s0 = atomicAdd(&cur[v4.x & (SPAN - 1)], 1u);
                uint32_t s1 = atomicAdd(&cur[v4.y & (SPAN - 1)], 1u);
                uint32_t s2 = atomicAdd(&cur[v4.z & (SPAN - 1)], 1u);
                uint32_t s3 = atomicAdd(&cur[v4.w & (SPAN - 1)], 1u);
                sort_buf[s0] = v4.x >> LSH;
                sort_buf[s1] = v4.y >> LSH;
                sort_buf[s2] = v4.z >> LSH;
                sort_buf[s3] = v4.w >> LSH;
            } else {
                for (uint32_t k = i; k < e; ++k) {
                    uint32_t v = bpack[k];
                    uint32_t slot = atomicAdd(&cur[v & (SPAN - 1)], 1u);
                    sort_buf[slot] = v >> LSH;
                }
            }
        }
        __syncthreads();
        uint32_t pro = as - s;  // elements before aligned base (0..3)
        if ((uint32_t)t < pro && (uint32_t)t < W) csr_row[s + t] = (int)sort_buf[t];
        for (uint32_t j = pro + ((uint32_t)t << 2); j < W; j += (PART_T << 2)) {
            if (j + 4u <= W) {
                *(int4*)(csr_row + s + j) =
                    make_int4((int)sort_buf[j], (int)sort_buf[j + 1],
                              (int)sort_buf[j + 2], (int)sort_buf[j + 3]);
            } else {
                for (uint32_t k = j; k < W; ++k) csr_row[s + k] = (int)sort_buf[k];
            }
        }
    } else {
        // statistical fallback (+17sigma): direct scattered stores
        for (uint32_t i = s + t; i < e; i += PART_T) {
            uint32_t v = bpack[i];
            uint32_t slot = atomicAdd(&cur[v & (SPAN - 1)], 1u);
            csr_row[s + slot] = (int)(v >> LSH);
        }
    }
}

// ---------------- node / gather kernels ----------------

// dxw1 = dinv * (x @ W1): 2 nodes per wave, float4 loads (1KB/wave),
// half-wave (32-lane) shuffle reduce.
__global__ __launch_bounds__(TPB) void k_xw1d(
    const float* __restrict__ x, const float* __restrict__ W1,
    const float* __restrict__ dinv, float* __restrict__ dxw1, int N) {
    __shared__ float sW[512];  // 128 x 4
    for (int t = threadIdx.x; t < 512; t += TPB) sW[t] = W1[t];
    __syncthreads();
    int gid  = blockIdx.x * TPB + threadIdx.x;
    int wave = gid >> 6;
    int lane = threadIdx.x & 63;
    int n    = wave * 2 + (lane >> 5);
    if (n >= N) return;
    float4 v = *(const float4*)(x + (size_t)wave * 256 + 4 * lane);
    const float* wb = &sW[(4 * (lane & 31)) * 4];
    float a[4];
#pragma unroll
    for (int j = 0; j < 4; ++j)
        a[j] = v.x * wb[0 * 4 + j] + v.y * wb[1 * 4 + j] +
               v.z * wb[2 * 4 + j] + v.w * wb[3 * 4 + j];
#pragma unroll
    for (int off = 16; off > 0; off >>= 1) {
#pragma unroll
        for (int j = 0; j < 4; ++j) a[j] += __shfl_xor(a[j], off);
    }
    if ((lane & 31) == 0) {
        float d = dinv[n];
        *(float4*)(dxw1 + (size_t)n * 4) =
            make_float4(d * a[0], d * a[1], d * a[2], d * a[3]);
    }
}

__global__ __launch_bounds__(TPB) void k_gather44(
    const unsigned int* __restrict__ indptr, const int* __restrict__ csr_row,
    const float* __restrict__ dinv, const float* __restrict__ dxw_in,
    const float* __restrict__ b, const float* __restrict__ W,
    float* __restrict__ dxw_out, int N) {
    int gid  = blockIdx.x * TPB + threadIdx.x;
    int node = gid >> 4;
    int sub  = gid & 15;
    if (node >= N) return;
    int e0 = (int)indptr[node], e1 = (int)indptr[node + 1];
    float4 acc = make_float4(0.f, 0.f, 0.f, 0.f);
    for (int j = e0 + sub; j < e1; j += 16) {
        int r = csr_row[j];
        float4 m = *(const float4*)(dxw_in + (size_t)r * 4);
        acc.x += m.x; acc.y += m.y; acc.z += m.z; acc.w += m.w;
    }
#pragma unroll
    for (int off = 1; off < 16; off <<= 1) {
        acc.x += __shfl_xor(acc.x, off);
        acc.y += __shfl_xor(acc.y, off);
        acc.z += __shfl_xor(acc.z, off);
        acc.w += __shfl_xor(acc.w, off);
    }
    if (sub == 0) {
        float d = dinv[node];
        float4 sv = *(const float4*)(dxw_in + (size_t)node * 4);
        float h0 = fmaxf(d * (acc.x + sv.x) + b[0], 0.f);
        float h1 = fmaxf(d * (acc.y + sv.y) + b[1], 0.f);
        float h2 = fmaxf(d * (acc.z + sv.z) + b[2], 0.f);
        float h3 = fmaxf(d * (acc.w + sv.w) + b[3], 0.f);
        float o[4];
#pragma unroll
        for (int j = 0; j < 4; ++j)
            o[j] = h0 * W[0 * 4 + j] + h1 * W[1 * 4 + j] +
                   h2 * W[2 * 4 + j] + h3 * W[3 * 4 + j];
        *(float4*)(dxw_out + (size_t)node * 4) =
            make_float4(d * o[0], d * o[1], d * o[2], d * o[3]);
    }
}

__global__ __launch_bounds__(TPB) void k_gather42(
    const unsigned int* __restrict__ indptr, const int* __restrict__ csr_row,
    const float* __restrict__ dinv, const float* __restrict__ dxw_in,
    const float* __restrict__ b, const float* __restrict__ W,
    float* __restrict__ dxw_out, int N) {
    int gid  = blockIdx.x * TPB + threadIdx.x;
    int node = gid >> 4;
    int sub  = gid & 15;
    if (node >= N) return;
    int e0 = (int)indptr[node], e1 = (int)indptr[node + 1];
    float4 acc = make_float4(0.f, 0.f, 0.f, 0.f);
    for (int j = e0 + sub; j < e1; j += 16) {
        int r = csr_row[j];
        float4 m = *(const float4*)(dxw_in + (size_t)r * 4);
        acc.x += m.x; acc.y += m.y; acc.z += m.z; acc.w += m.w;
    }
#pragma unroll
    for (int off = 1; off < 16; off <<= 1) {
        acc.x += __shfl_xor(acc.x, off);
        acc.y += __shfl_xor(acc.y, off);
        acc.z += __shfl_xor(acc.z, off);
        acc.w += __shfl_xor(acc.w, off);
    }
    if (sub == 0) {
        float d = dinv[node];
        float4 sv = *(const float4*)(dxw_in + (size_t)node * 4);
        float h0 = fmaxf(d * (acc.x + sv.x) + b[0], 0.f);
        float h1 = fmaxf(d * (acc.y + sv.y) + b[1], 0.f);
        float h2 = fmaxf(d * (acc.z + sv.z) + b[2], 0.f);
        float h3 = fmaxf(d * (acc.w + sv.w) + b[3], 0.f);
        float o0 = h0 * W[0] + h1 * W[2] + h2 * W[4] + h3 * W[6];
        float o1 = h0 * W[1] + h1 * W[3] + h2 * W[5] + h3 * W[7];
        *(float2*)(dxw_out + (size_t)node * 2) = make_float2(d * o0, d * o1);
    }
}

__global__ __launch_bounds__(TPB) void k_gather2out(
    const unsigned int* __restrict__ indptr, const int* __restrict__ csr_row,
    const float* __restrict__ dinv, const float* __restrict__ dxw3,
    const float* __restrict__ b3, const float* __restrict__ Wc,
    const float* __restrict__ bc,
    float* __restrict__ out, float* __restrict__ y3out, int N) {
    int gid  = blockIdx.x * TPB + threadIdx.x;
    int node = gid >> 4;
    int sub  = gid & 15;
    if (node >= N) return;
    int e0 = (int)indptr[node], e1 = (int)indptr[node + 1];
    float ax = 0.f, ay = 0.f;
    for (int j = e0 + sub; j < e1; j += 16) {
        int r = csr_row[j];
        float2 m = *(const float2*)(dxw3 + (size_t)r * 2);
        ax += m.x; ay += m.y;
    }
#pragma unroll
    for (int off = 1; off < 16; off <<= 1) {
        ax += __shfl_xor(ax, off);
        ay += __shfl_xor(ay, off);
    }
    if (sub == 0) {
        float d = dinv[node];
        float2 sv = *(const float2*)(dxw3 + (size_t)node * 2);
        float y0 = fmaxf(d * (ax + sv.x) + b3[0], 0.f);
        float y1 = fmaxf(d * (ay + sv.y) + b3[1], 0.f);
        float o[4];
#pragma unroll
        for (int j = 0; j < 4; ++j)
            o[j] = y0 * Wc[0 * 4 + j] + y1 * Wc[1 * 4 + j] + bc[j];
        *(float4*)(out + (size_t)node * 4) = make_float4(o[0], o[1], o[2], o[3]);
        *(float2*)(y3out + (size_t)node * 2) = make_float2(y0, y1);
    }
}

// ---------------- R3 fallback kernels (atomic push path) ----------------

__global__ __launch_bounds__(TPB) void k_zero_deg(unsigned int* __restrict__ deg, int N) {
    int i = blockIdx.x * TPB + threadIdx.x;
    if (i < N) deg[i] = 0u;
}

__global__ __launch_bounds__(TPB) void k_deg(
    const int* __restrict__ col, unsigned int* __restrict__ deg, int E) {
    int e = blockIdx.x * TPB + threadIdx.x;
    if (e >= E) return;
    atomicAdd(&deg[col[e]], 1u);
}

__global__ __launch_bounds__(TPB) void k_dinv(const unsigned int* __restrict__ deg,
                                              float* __restrict__ dinv, int N) {
    int i = blockIdx.x * TPB + threadIdx.x;
    if (i < N) dinv[i] = rsqrtf((float)(deg[i] + 1u));
}

__global__ __launch_bounds__(TPB) void k_xw1(
    const float* __restrict__ x, const float* __restrict__ W1,
    const float* __restrict__ dinv,
    float* __restrict__ xw, float* __restrict__ agg, int N) {
    __shared__ float sW[512];
    for (int t = threadIdx.x; t < 512; t += TPB) sW[t] = W1[t];
    __syncthreads();
    int gid  = blockIdx.x * TPB + threadIdx.x;
    int node = gid >> 6;
    int lane = threadIdx.x & 63;
    if (node >= N) return;
    float2 v = *(const float2*)(x + (size_t)node * 128 + 2 * lane);
    const float* w0 = &sW[(2 * lane) * 4];
    const float* w1 = &sW[(2 * lane + 1) * 4];
    float a[4];
#pragma unroll
    for (int j = 0; j < 4; ++j) a[j] = v.x * w0[j] + v.y * w1[j];
#pragma unroll
    for (int off = 32; off > 0; off >>= 1) {
#pragma unroll
        for (int j = 0; j < 4; ++j) a[j] += __shfl_down(a[j], off);
    }
    if (lane == 0) {
        float d  = dinv[node];
        float d2 = d * d;
        *(float4*)(xw  + (size_t)node * 4) = make_float4(a[0], a[1], a[2], a[3]);
        *(float4*)(agg + (size_t)node * 4) =
            make_float4(d2 * a[0], d2 * a[1], d2 * a[2], d2 * a[3]);
    }
}

__global__ __launch_bounds__(TPB) void k_prop4(
    const int* __restrict__ row, const int* __restrict__ col,
    const float* __restrict__ dinv,
    const float* __restrict__ xw, float* __restrict__ agg, int E) {
    int e = blockIdx.x * TPB + threadIdx.x;
    if (e >= E) return;
    int r = row[e];
    int c = col[e];
    float nv = dinv[r] * dinv[c];
    float4 m = *(const float4*)(xw + (size_t)r * 4);
    float* a = agg + (size_t)c * 4;
    atomicAdd(a + 0, nv * m.x);
    atomicAdd(a + 1, nv * m.y);
    atomicAdd(a + 2, nv * m.z);
    atomicAdd(a + 3, nv * m.w);
}

__global__ __launch_bounds__(TPB) void k_prop2(
    const int* __restrict__ row, const int* __restrict__ col,
    const float* __restrict__ dinv,
    const float* __restrict__ xw2, float* __restrict__ agg2, int E) {
    int e = blockIdx.x * TPB + threadIdx.x;
    if (e >= E) return;
    int r = row[e];
    int c = col[e];
    float nv = dinv[r] * dinv[c];
    float2 m = *(const float2*)(xw2 + (size_t)r * 2);
    float* a = agg2 + (size_t)c * 2;
    atomicAdd(a + 0, nv * m.x);
    atomicAdd(a + 1, nv * m.y);
}

__global__ __launch_bounds__(TPB) void k_node2(
    const float* __restrict__ b1, const float* __restrict__ W2,
    const float* __restrict__ dinv,
    float* __restrict__ xw, float* __restrict__ agg, int N) {
    int i = blockIdx.x * TPB + threadIdx.x;
    if (i >= N) return;
    float4 av = *(const float4*)(agg + (size_t)i * 4);
    float h0 = fmaxf(av.x + b1[0], 0.f);
    float h1 = fmaxf(av.y + b1[1], 0.f);
    float h2 = fmaxf(av.z + b1[2], 0.f);
    float h3 = fmaxf(av.w + b1[3], 0.f);
    float o[4];
#pragma unroll
    for (int j = 0; j < 4; ++j)
        o[j] = h0 * W2[0 * 4 + j] + h1 * W2[1 * 4 + j] +
               h2 * W2[2 * 4 + j] + h3 * W2[3 * 4 + j];
    float d  = dinv[i];
    float d2 = d * d;
    *(float4*)(xw  + (size_t)i * 4) = make_float4(o[0], o[1], o[2], o[3]);
    *(float4*)(agg + (size_t)i * 4) = make_float4(d2 * o[0], d2 * o[1], d2 * o[2], d2 * o[3]);
}

__global__ __launch_bounds__(TPB) void k_node3(
    const float* __restrict__ b2, const float* __restrict__ W3,
    const float* __restrict__ dinv,
    const float* __restrict__ agg,
    float* __restrict__ xw3, float* __restrict__ agg3, int N) {
    int i = blockIdx.x * TPB + threadIdx.x;
    if (i >= N) return;
    float4 av = *(const float4*)(agg + (size_t)i * 4);
    float h0 = fmaxf(av.x + b2[0], 0.f);
    float h1 = fmaxf(av.y + b2[1], 0.f);
    float h2 = fmaxf(av.z + b2[2], 0.f);
    float h3 = fmaxf(av.w + b2[3], 0.f);
    float o0 = h0 * W3[0] + h1 * W3[2] + h2 * W3[4] + h3 * W3[6];
    float o1 = h0 * W3[1] + h1 * W3[3] + h2 * W3[5] + h3 * W3[7];
    float d  = dinv[i];
    float d2 = d * d;
    *(float2*)(xw3  + (size_t)i * 2) = make_float2(o0, o1);
    *(float2*)(agg3 + (size_t)i * 2) = make_float2(d2 * o0, d2 * o1);
}

__global__ __launch_bounds__(TPB) void k_out(
    const float* __restrict__ b3, const float* __restrict__ Wc,
    const float* __restrict__ bc,
    const float* __restrict__ agg3,
    float* __restrict__ out, float* __restrict__ y3out, int N) {
    int i = blockIdx.x * TPB + threadIdx.x;
    if (i >= N) return;
    float2 av = *(const float2*)(agg3 + (size_t)i * 2);
    float y0 = fmaxf(av.x + b3[0], 0.f);
    float y1 = fmaxf(av.y + b3[1], 0.f);
    float o[4];
#pragma unroll
    for (int j = 0; j < 4; ++j)
        o[j] = y0 * Wc[0 * 4 + j] + y1 * Wc[1 * 4 + j] + bc[j];
    *(float4*)(out + (size_t)i * 4) = make_float4(o[0], o[1], o[2], o[3]);
    *(float2*)(y3out + (size_t)i * 2) = make_float2(y0, y1);
}

extern "C" void kernel_launch(void* const* d_in, const int* in_sizes, int n_in,
                              void* d_out, int out_size, void* d_ws, size_t ws_size,
                              hipStream_t stream) {
    const float* x  = (const float*)d_in[0];
    const int*   ei = (const int*)d_in[1];   // int32 (harness converts integer inputs)
    const float* W1 = (const float*)d_in[2];
    const float* b1 = (const float*)d_in[3];
    const float* W2 = (const float*)d_in[4];
    const float* b2 = (const float*)d_in[5];
    const float* W3 = (const float*)d_in[6];
    const float* b3 = (const float*)d_in[7];
    const float* Wc = (const float*)d_in[8];
    const float* bc = (const float*)d_in[9];

    const int N = in_sizes[0] / 128;
    const int E = in_sizes[1] / 2;

    const int* row = ei;
    const int* col = ei + (size_t)E;

    const int NB  = (N + SPAN - 1) / SPAN;        // dest buckets (196)
    const int M   = NB * PART_B;                  // flattened hist size (~50K)
    const int PBE = (E + PART_B - 1) / PART_B;    // edges per partition block

    float* out   = (float*)d_out;                  // [N,4]
    float* y3out = (float*)d_out + (size_t)N * 4;  // [N,2]

    const int nblkN  = (N + TPB - 1) / TPB;
    const int nblkE  = (E + TPB - 1) / TPB;
    const int nblkW  = (N * 64 + TPB - 1) / TPB;          // wave-per-node (fallback)
    const int nblkX  = (((N + 1) / 2) * 64 + TPB - 1) / TPB;  // 2 nodes/wave
    const int nblkG  = (N * 16 + TPB - 1) / TPB;          // 16 threads/node
    const int nblkM  = (M + 1 + TPB - 1) / TPB;
    const int nblkS  = (M + SCAN_B - 1) / SCAN_B;         // scan blocks (~13)

    // Carve (~56.2MB). H is scanned in place (becomes O).
    size_t off = 0;
    auto carve = [&](size_t bytes) -> void* {
        void* r = (void*)((char*)d_ws + off);
        off += (bytes + 255) & ~(size_t)255;
        return r;
    };
    float*        dinv    = (float*)carve((size_t)N * 4);
    float*        dxw1    = (float*)carve((size_t)N * 4 * 4);
    float*        dxw2    = (float*)carve((size_t)N * 4 * 4);
    float*        dxw3    = (float*)carve((size_t)N * 2 * 4);
    unsigned int* indptr  = (unsigned int*)carve(((size_t)N + 1) * 4);
    uint32_t*     bsum    = (uint32_t*)carve(260 * 4);
    uint32_t*     H       = (uint32_t*)carve(((size_t)M + 1) * 4);  // -> O in place
    uint32_t*     bpack   = (uint32_t*)carve((size_t)E * 4);
    int*          csr_row = (int*)carve((size_t)E * 4);
    bool use_bucket = (off <= ws_size) && (NB <= 1024) && (N < (1 << 23));

    if (use_bucket) {
        size_t sort_lds = (size_t)SORT_CAP * 4;  // 140KB dynamic (+4KB static)
        hipFuncSetAttribute((const void*)p_sort,
                            hipFuncAttributeMaxDynamicSharedMemorySize,
                            (int)sort_lds);
        p_hist<<<PART_B, PART_T, 0, stream>>>(col, H, NB, E, PBE);
        k_scan1<<<nblkS, SCAN_T, 0, stream>>>(H, H, bsum, M);         // in-place
        k_scan2<<<1, 32, 0, stream>>>(bsum, nblkS);
        k_scan3<<<nblkM, TPB, 0, stream>>>(H, bsum, H, M, E);         // in-place
        p_part<<<PART_B, PART_T, 0, stream>>>(row, col, H, bpack, NB, E, PBE);
        p_sort<<<NB, PART_T, sort_lds, stream>>>(bpack, H, csr_row, indptr,
                                                 dinv, NB, N, E);
        k_xw1d<<<nblkX, TPB, 0, stream>>>(x, W1, dinv, dxw1, N);
        k_gather44<<<nblkG, TPB, 0, stream>>>(indptr, csr_row, dinv, dxw1, b1, W2, dxw2, N);
        k_gather42<<<nblkG, TPB, 0, stream>>>(indptr, csr_row, dinv, dxw2, b2, W3, dxw3, N);
        k_gather2out<<<nblkG, TPB, 0, stream>>>(indptr, csr_row, dinv, dxw3, b3, Wc, bc,
                                                out, y3out, N);
    } else {
        // R3 verified atomic-push fallback: recarve from base (~6MB).
        size_t foff = 0;
        auto fcarve = [&](size_t bytes) -> void* {
            void* r = (void*)((char*)d_ws + foff);
            foff += (bytes + 255) & ~(size_t)255;
            return r;
        };
        unsigned int* deg   = (unsigned int*)fcarve((size_t)N * 4);
        float*        fdinv = (float*)fcarve((size_t)N * 4);
        float*        xw    = (float*)fcarve((size_t)N * 4 * 4);
        float*        agg   = (float*)fcarve((size_t)N * 4 * 4);
        float*        xw3   = (float*)fcarve((size_t)N * 2 * 4);
        float*        agg3  = (float*)fcarve((size_t)N * 2 * 4);
        k_zero_deg<<<nblkN, TPB, 0, stream>>>(deg, N);
        k_deg<<<nblkE, TPB, 0, stream>>>(col, deg, E);
        k_dinv<<<nblkN, TPB, 0, stream>>>(deg, fdinv, N);
        k_xw1<<<nblkW, TPB, 0, stream>>>(x, W1, fdinv, xw, agg, N);
        k_prop4<<<nblkE, TPB, 0, stream>>>(row, col, fdinv, xw, agg, E);
        k_node2<<<nblkN, TPB, 0, stream>>>(b1, W2, fdinv, xw, agg, N);
        k_prop4<<<nblkE, TPB, 0, stream>>>(row, col, fdinv, xw, agg, E);
        k_node3<<<nblkN, TPB, 0, stream>>>(b2, W3, fdinv, agg, xw3, agg3, N);
        k_prop2<<<nblkE, TPB, 0, stream>>>(row, col, fdinv, xw3, agg3, E);
        k_out<<<nblkN, TPB, 0, stream>>>(b3, Wc, bc, agg3, out, y3out, N);
    }
}